// Round 3
// baseline (2855.557 us; speedup 1.0000x reference)
//
#include <hip/hip_runtime.h>
#include <hip/hip_bf16.h>
#include <math.h>

typedef __hip_bfloat16 bf16;

static constexpr int B_  = 4;
static constexpr int Hh  = 112, Ww = 112;
static constexpr int Nn  = Hh * Ww;        // 12544
static constexpr int Cc  = 256;
static constexpr int M_  = B_ * Nn;        // 50176
static constexpr int GH_ = 4;
static constexpr int GD_ = 128;
static constexpr int LD_ = 128;
static constexpr int HID_ = 1024;
static constexpr int TG_ = 256;            // 16*16 windows
static constexpr int T__ = 49;             // 7*7 tokens per window
static constexpr float SCALE_ = 0.17677669529663687f;  // 32^-0.5

__device__ __forceinline__ float toF(const bf16 v)  { return __bfloat162float(v); }
__device__ __forceinline__ float toF(const float v) { return v; }
__device__ __forceinline__ void st_out(float* p, float v) { *p = v; }
__device__ __forceinline__ void st_out(bf16* p, float v)  { *p = __float2bfloat16(v); }

// windowed row r = ((b*256 + g)*49 + t)  ->  flat row b*N + n
__device__ __forceinline__ int win_row_map(int r) {
  int b  = r / Nn;
  int rr = r - b * Nn;
  int g  = rr / T__;
  int t  = rr - g * T__;
  int gh = g >> 4, gw = g & 15;
  int i  = t / 7,  j  = t - i * 7;
  int n  = (gh * 7 + i) * Ww + gw * 7 + j;
  return b * Nn + n;
}

__global__ void guard_fill_kernel(float* out) {
  out[threadIdx.x + blockIdx.x * 256] = 1.0e6f;  // sentinel: workspace guard tripped
}

// ---------------- LayerNorm (one block per row of 256 channels) ----------------
template <typename T>
__global__ __launch_bounds__(256) void ln_kernel(const T* __restrict__ x,
                                                 const float* __restrict__ g,
                                                 const float* __restrict__ bta,
                                                 bf16* __restrict__ out) {
  const int row = blockIdx.x;
  const int tid = threadIdx.x;
  float v = toF(x[(size_t)row * Cc + tid]);
  float s = v, ss = v * v;
  #pragma unroll
  for (int off = 32; off > 0; off >>= 1) {
    s  += __shfl_down(s, off);
    ss += __shfl_down(ss, off);
  }
  __shared__ float rbuf[8];
  const int lane = tid & 63, wid = tid >> 6;
  if (lane == 0) { rbuf[wid] = s; rbuf[4 + wid] = ss; }
  __syncthreads();
  float ts  = rbuf[0] + rbuf[1] + rbuf[2] + rbuf[3];
  float tss = rbuf[4] + rbuf[5] + rbuf[6] + rbuf[7];
  float mean = ts * (1.0f / Cc);
  float var  = tss * (1.0f / Cc) - mean * mean;
  float r = rsqrtf(var + 1e-5f);
  float o = (v - mean) * r * g[tid] + bta[tid];
  out[(size_t)row * Cc + tid] = __float2bfloat16(o);
}

// ---------------- 7x7 average pool of xrn -> pooled (B,256,C) ----------------
__global__ __launch_bounds__(256) void pool_kernel(const bf16* __restrict__ xrn,
                                                   bf16* __restrict__ pooled) {
  const int c  = threadIdx.x;
  const int g  = blockIdx.x;   // gh*16+gw
  const int b  = blockIdx.y;
  const int gh = g >> 4, gw = g & 15;
  float s = 0.f;
  #pragma unroll
  for (int i = 0; i < 7; i++)
    for (int j = 0; j < 7; j++) {
      int n = (gh * 7 + i) * Ww + gw * 7 + j;
      s += toF(xrn[((size_t)b * Nn + n) * Cc + c]);
    }
  pooled[((size_t)b * TG_ + g) * Cc + c] = __float2bfloat16(s * (1.0f / 49.0f));
}

// ---------------- tiled GEMM: out[M,N] = A[M,K] @ W[K,N] + bias (+res) ----------------
// A is bf16 intermediate; W/bias are fp32 model weights.
template <typename OutT, bool WIN_A, bool RES>
__global__ __launch_bounds__(256) void gemm_kernel(const bf16* __restrict__ A,
                                                   const float* __restrict__ W,
                                                   const float* __restrict__ bias,
                                                   const float* __restrict__ res,
                                                   OutT* __restrict__ out,
                                                   int M, int N, int K) {
  __shared__ float As[64][33];
  __shared__ float Bs[32][65];
  const int bm = blockIdx.y * 64, bn = blockIdx.x * 64;
  const int tid = threadIdx.x;
  const int tx = tid & 15, ty = tid >> 4;
  const int ar = tid >> 2, ac0 = (tid & 3) * 8;
  const int wr = tid >> 3, wc0 = (tid & 7) * 8;
  int arow = bm + ar;
  int asrc = WIN_A ? win_row_map(arow) : arow;
  const bf16*  Ap = A + (size_t)asrc * K + ac0;
  const float* Wp = W + (size_t)wr * N + bn + wc0;
  float acc[4][4] = {};
  for (int k0 = 0; k0 < K; k0 += 32) {
    #pragma unroll
    for (int i = 0; i < 8; i++) As[ar][ac0 + i] = toF(Ap[i]);
    #pragma unroll
    for (int i = 0; i < 8; i++) Bs[wr][wc0 + i] = Wp[i];
    Ap += 32;
    Wp += (size_t)32 * N;
    __syncthreads();
    #pragma unroll
    for (int kk = 0; kk < 32; kk++) {
      float a[4], bb[4];
      #pragma unroll
      for (int i = 0; i < 4; i++) a[i] = As[ty * 4 + i][kk];
      #pragma unroll
      for (int j = 0; j < 4; j++) bb[j] = Bs[kk][tx * 4 + j];
      #pragma unroll
      for (int i = 0; i < 4; i++)
        #pragma unroll
        for (int j = 0; j < 4; j++) acc[i][j] = fmaf(a[i], bb[j], acc[i][j]);
    }
    __syncthreads();
  }
  #pragma unroll
  for (int i = 0; i < 4; i++) {
    int row = bm + ty * 4 + i;
    size_t ro = (size_t)row * N + bn + tx * 4;
    #pragma unroll
    for (int j = 0; j < 4; j++) {
      float v = acc[i][j] + bias[bn + tx * 4 + j];
      if (RES) v += res[ro + j];
      st_out(out + ro + j, v);
    }
  }
}

// ---------------- global attention (online softmax, 64-key chunks) ----------------
// q (B*N,128) bf16 x kv (B*256,256) bf16 -> out bf16 (B*N,128)
__global__ __launch_bounds__(256) void gattn_kernel(const bf16* __restrict__ q,
                                                    const bf16* __restrict__ kv,
                                                    bf16* __restrict__ out) {
  __shared__ float ks[64 * 32];
  __shared__ float vs[64 * 32];
  const int tid = threadIdx.x;
  const int h = blockIdx.y, b = blockIdx.z;
  const bf16* kvb = kv + (size_t)b * TG_ * 256;
  const int n = blockIdx.x * 256 + tid;
  const size_t qoff = ((size_t)b * Nn + n) * GD_ + h * 32;
  float qv[32];
  #pragma unroll
  for (int d = 0; d < 32; d++) qv[d] = toF(q[qoff + d]) * SCALE_;
  float mx = -1e30f, l = 0.f;
  float acc[32] = {};
  for (int c0 = 0; c0 < 256; c0 += 64) {
    for (int idx = tid; idx < 64 * 32; idx += 256) {
      int m = idx >> 5, d = idx & 31;
      ks[idx] = toF(kvb[(size_t)(c0 + m) * 256 + h * 32 + d]);
      vs[idx] = toF(kvb[(size_t)(c0 + m) * 256 + 128 + h * 32 + d]);
    }
    __syncthreads();
    float cmx = -1e30f;
    for (int m = 0; m < 64; m++) {
      const float* kr = ks + m * 32;
      float s = 0.f;
      #pragma unroll
      for (int d = 0; d < 32; d++) s = fmaf(qv[d], kr[d], s);
      cmx = fmaxf(cmx, s);
    }
    float nmx = fmaxf(mx, cmx);
    float sc = __expf(mx - nmx);
    l *= sc;
    #pragma unroll
    for (int d = 0; d < 32; d++) acc[d] *= sc;
    mx = nmx;
    for (int m = 0; m < 64; m++) {
      const float* kr = ks + m * 32;
      const float* vr = vs + m * 32;
      float s = 0.f;
      #pragma unroll
      for (int d = 0; d < 32; d++) s = fmaf(qv[d], kr[d], s);
      float p = __expf(s - mx);
      l += p;
      #pragma unroll
      for (int d = 0; d < 32; d++) acc[d] = fmaf(p, vr[d], acc[d]);
    }
    __syncthreads();
  }
  const float rl = 1.0f / l;
  #pragma unroll
  for (int d = 0; d < 32; d++) out[qoff + d] = __float2bfloat16(acc[d] * rl);
}

// ---------------- local window attention: one wave per (b, window, head) ----------------
__global__ __launch_bounds__(64) void lattn_kernel(const bf16* __restrict__ ql,
                                                   const bf16* __restrict__ kvl,
                                                   bf16* __restrict__ out) {
  __shared__ float ks[T__ * 32];
  __shared__ float vs[T__ * 32];
  const int tid = threadIdx.x;
  const int h = blockIdx.x, g = blockIdx.y, b = blockIdx.z;
  const size_t base = (((size_t)b * TG_ + g) * T__) * 256;
  for (int idx = tid; idx < T__ * 32; idx += 64) {
    int m = idx >> 5, d = idx & 31;
    ks[idx] = toF(kvl[base + (size_t)m * 256 + h * 32 + d]);
    vs[idx] = toF(kvl[base + (size_t)m * 256 + 128 + h * 32 + d]);
  }
  __syncthreads();
  if (tid < T__) {
    const size_t qoff = (((size_t)b * TG_ + g) * T__ + tid) * LD_ + h * 32;
    float qv[32];
    #pragma unroll
    for (int d = 0; d < 32; d++) qv[d] = toF(ql[qoff + d]) * SCALE_;
    float mx = -1e30f;
    for (int m = 0; m < T__; m++) {
      const float* kr = ks + m * 32;
      float s = 0.f;
      #pragma unroll
      for (int d = 0; d < 32; d++) s = fmaf(qv[d], kr[d], s);
      mx = fmaxf(mx, s);
    }
    float l = 0.f;
    float acc[32] = {};
    for (int m = 0; m < T__; m++) {
      const float* kr = ks + m * 32;
      const float* vr = vs + m * 32;
      float s = 0.f;
      #pragma unroll
      for (int d = 0; d < 32; d++) s = fmaf(qv[d], kr[d], s);
      float p = __expf(s - mx);
      l += p;
      #pragma unroll
      for (int d = 0; d < 32; d++) acc[d] = fmaf(p, vr[d], acc[d]);
    }
    const float rl = 1.0f / l;
    #pragma unroll
    for (int d = 0; d < 32; d++) out[qoff + d] = __float2bfloat16(acc[d] * rl);
  }
}

// ---------------- combine: xres = x + concat(gout, un-windowed lo) ----------------
__global__ __launch_bounds__(256) void combine_kernel(const float* __restrict__ x,
                                                      const bf16* __restrict__ gout,
                                                      const bf16* __restrict__ lo_w,
                                                      float* __restrict__ xres) {
  const int row = blockIdx.x;  // b*N + n
  const int c = threadIdx.x;
  float base = x[(size_t)row * Cc + c];
  float add;
  if (c < 128) {
    add = toF(gout[(size_t)row * GD_ + c]);
  } else {
    int b = row / Nn, n = row - b * Nn;
    int y = n / Ww, xx = n - y * Ww;
    int gh = y / 7, i = y - gh * 7;
    int gw = xx / 7, j = xx - gw * 7;
    size_t wrow = ((size_t)b * TG_ + gh * 16 + gw) * T__ + i * 7 + j;
    add = toF(lo_w[wrow * LD_ + (c - 128)]);
  }
  xres[(size_t)row * Cc + c] = base + add;
}

// ---------------- depthwise 3x3 conv (SAME) + bias + exact GELU, single batch ----------------
__global__ __launch_bounds__(256) void dwconv_gelu_kernel(const bf16* __restrict__ h1,
                                                          const float* __restrict__ w,
                                                          const float* __restrict__ bias,
                                                          bf16* __restrict__ h2) {
  const int n = blockIdx.x;            // n within one batch image
  const int y = n / Ww, x = n - y * Ww;
  const int c0 = threadIdx.x * 4;
  float acc[4] = {};
  #pragma unroll
  for (int di = -1; di <= 1; di++) {
    int yy = y + di;
    if (yy < 0 || yy >= Hh) continue;
    #pragma unroll
    for (int dj = -1; dj <= 1; dj++) {
      int xx = x + dj;
      if (xx < 0 || xx >= Ww) continue;
      size_t off = ((size_t)(yy * Ww + xx)) * HID_ + c0;
      #pragma unroll
      for (int u = 0; u < 4; u++)
        acc[u] = fmaf(toF(h1[off + u]), w[(c0 + u) * 9 + (di + 1) * 3 + (dj + 1)], acc[u]);
    }
  }
  size_t oo = (size_t)n * HID_ + c0;
  #pragma unroll
  for (int u = 0; u < 4; u++) {
    float v = acc[u] + bias[c0 + u];
    float gl = 0.5f * v * (1.0f + erff(v * 0.7071067811865475f));
    h2[oo + u] = __float2bfloat16(gl);
  }
}

extern "C" void kernel_launch(void* const* d_in, const int* in_sizes, int n_in,
                              void* d_out, int out_size, void* d_ws, size_t ws_size,
                              hipStream_t stream) {
  // Reference dtypes are float32 — cast accordingly (documented harness contract).
  const float* x     = (const float*)d_in[0];
  const float* xrev  = (const float*)d_in[1];
  const float* g1    = (const float*)d_in[2];
  const float* b1    = (const float*)d_in[3];
  const float* g2    = (const float*)d_in[4];
  const float* b2    = (const float*)d_in[5];
  const float* Gq_w  = (const float*)d_in[6];
  const float* Gq_b  = (const float*)d_in[7];
  const float* Gkv_w = (const float*)d_in[8];
  const float* Gkv_b = (const float*)d_in[9];
  const float* Gp_w  = (const float*)d_in[10];
  const float* Gp_b  = (const float*)d_in[11];
  const float* Lq_w  = (const float*)d_in[12];
  const float* Lq_b  = (const float*)d_in[13];
  const float* Lkv_w = (const float*)d_in[14];
  const float* Lkv_b = (const float*)d_in[15];
  const float* Lp_w  = (const float*)d_in[16];
  const float* Lp_b  = (const float*)d_in[17];
  const float* fc1_w = (const float*)d_in[18];
  const float* fc1_b = (const float*)d_in[19];
  const float* dw_w  = (const float*)d_in[20];
  const float* dw_b  = (const float*)d_in[21];
  const float* fc2_w = (const float*)d_in[22];
  const float* fc2_b = (const float*)d_in[23];
  // d_in[24]=H, d_in[25]=W — constants (112) baked in.

  // ---- workspace layout: bf16 intermediates + lifetime-aliased slots (~142 MB) ----
  const size_t SZ_XRES = (size_t)M_ * Cc * 4;        // 51,380,224  fp32, lives steps 11-15
  const size_t SZ_ROW2 = (size_t)M_ * Cc * 2;        // 25,690,112  (256-col bf16)
  const size_t SZ_HALF = (size_t)M_ * 128 * 2;       // 12,845,056  (128-col bf16)
  const size_t SZ_POOL = (size_t)B_ * TG_ * Cc * 2;  //    524,288
  const size_t SZ_KVG  = (size_t)B_ * TG_ * 256 * 2; //    524,288

  char* ws = (char*)d_ws;
  float* xres  = (float*)ws;
  char*  arena = ws + SZ_XRES;
  // slot S1: xn [steps 1-7] -> kvl [8-9]
  // slot S2: xrn [1-8]      -> lo_w [10-11]
  // slot S3: q  [3-5]       -> ql   [7-9]
  // slot S4: gattn [5-6]    -> lattn[9-10]
  // slot S5: gout [6-11]
  bf16* S1 = (bf16*)(arena);
  bf16* S2 = (bf16*)(arena + SZ_ROW2);
  bf16* S3 = (bf16*)(arena + 2 * SZ_ROW2);
  bf16* S4 = (bf16*)(arena + 2 * SZ_ROW2 + SZ_HALF);
  bf16* S5 = (bf16*)(arena + 2 * SZ_ROW2 + 2 * SZ_HALF);
  bf16* poolb = (bf16*)(arena + 2 * SZ_ROW2 + 3 * SZ_HALF);
  bf16* kvG   = (bf16*)(arena + 2 * SZ_ROW2 + 3 * SZ_HALF + SZ_POOL);
  const size_t ARENA_BYTES = 2 * SZ_ROW2 + 3 * SZ_HALF + SZ_POOL + SZ_KVG;  // ~90.7 MB
  // phase B (per-batch MLP) aliases the whole arena (dead after step 11):
  bf16* xn2 = (bf16*)(arena);                                     //  6.4 MB
  bf16* h1  = (bf16*)(arena + (size_t)Nn * Cc * 2);               // 25.7 MB
  bf16* h2  = (bf16*)(arena + (size_t)Nn * Cc * 2 + (size_t)Nn * HID_ * 2);  // 25.7 MB

  float* out = (float*)d_out;
  if (ws_size < SZ_XRES + ARENA_BYTES) {  // needs ~142 MB
    guard_fill_kernel<<<16, 256, 0, stream>>>(out);  // sentinel 1e6 -> diagnosable
    return;
  }

  bf16* xn = S1;  bf16* xrn = S2;  bf16* qbuf = S3;  bf16* gattn = S4;  bf16* gout = S5;
  bf16* kvl = S1; bf16* lo_w = S2; bf16* qlb  = S3;  bf16* lattn = S4;

  // 1) LayerNorm both streams
  ln_kernel<float><<<M_, 256, 0, stream>>>(x, g1, b1, xn);
  ln_kernel<float><<<M_, 256, 0, stream>>>(xrev, g1, b1, xrn);
  // 2) 7x7 pool of xrn
  pool_kernel<<<dim3(TG_, B_), 256, 0, stream>>>(xrn, poolb);
  // 3) q = xn @ Gq_w + b
  gemm_kernel<bf16, false, false><<<dim3(GD_ / 64, M_ / 64), 256, 0, stream>>>(
      xn, Gq_w, Gq_b, nullptr, qbuf, M_, GD_, Cc);
  // 4) kv = pooled @ Gkv_w + b
  gemm_kernel<bf16, false, false><<<dim3(256 / 64, (B_ * TG_) / 64), 256, 0, stream>>>(
      poolb, Gkv_w, Gkv_b, nullptr, kvG, B_ * TG_, 256, Cc);
  // 5) global attention
  gattn_kernel<<<dim3(Nn / 256, GH_, B_), 256, 0, stream>>>(qbuf, kvG, gattn);
  // 6) gout = gattn @ Gp_w + b
  gemm_kernel<bf16, false, false><<<dim3(GD_ / 64, M_ / 64), 256, 0, stream>>>(
      gattn, Gp_w, Gp_b, nullptr, gout, M_, GD_, GD_);
  // 7) ql = windows(xn) @ Lq_w + b
  gemm_kernel<bf16, true, false><<<dim3(LD_ / 64, M_ / 64), 256, 0, stream>>>(
      xn, Lq_w, Lq_b, nullptr, qlb, M_, LD_, Cc);
  // 8) kvl = windows(xrn) @ Lkv_w + b   (writes over xn slot — xn dead after step 7)
  gemm_kernel<bf16, true, false><<<dim3(256 / 64, M_ / 64), 256, 0, stream>>>(
      xrn, Lkv_w, Lkv_b, nullptr, kvl, M_, 256, Cc);
  // 9) local attention
  lattn_kernel<<<dim3(4, TG_, B_), 64, 0, stream>>>(qlb, kvl, lattn);
  // 10) lo = lattn @ Lp_w + b   (windowed row order; writes over xrn slot)
  gemm_kernel<bf16, false, false><<<dim3(LD_ / 64, M_ / 64), 256, 0, stream>>>(
      lattn, Lp_w, Lp_b, nullptr, lo_w, M_, LD_, LD_);
  // 11) xres = x + concat(gout, unwindow(lo))
  combine_kernel<<<M_, 256, 0, stream>>>(x, gout, lo_w, xres);
  // 12-15) MLP per batch (keeps h1/h2 at 1/4 size)
  for (int b = 0; b < B_; b++) {
    const float* xres_b = xres + (size_t)b * Nn * Cc;
    float* out_b = out + (size_t)b * Nn * Cc;
    ln_kernel<float><<<Nn, 256, 0, stream>>>(xres_b, g2, b2, xn2);
    gemm_kernel<bf16, false, false><<<dim3(HID_ / 64, Nn / 64), 256, 0, stream>>>(
        xn2, fc1_w, fc1_b, nullptr, h1, Nn, HID_, Cc);
    dwconv_gelu_kernel<<<Nn, 256, 0, stream>>>(h1, dw_w, dw_b, h2);
    gemm_kernel<float, false, true><<<dim3(Cc / 64, Nn / 64), 256, 0, stream>>>(
        h2, fc2_w, fc2_b, xres_b, out_b, Nn, Cc, HID_);
  }
}

// Round 4
// 1416.690 us; speedup vs baseline: 2.0157x; 2.0157x over previous
//
#include <hip/hip_runtime.h>
#include <hip/hip_bf16.h>
#include <math.h>

typedef __hip_bfloat16 bf16;
typedef __attribute__((ext_vector_type(8))) short bf16x8;
typedef __attribute__((ext_vector_type(4))) float f32x4;

static constexpr int B_  = 4;
static constexpr int Hh  = 112, Ww = 112;
static constexpr int Nn  = Hh * Ww;        // 12544
static constexpr int Cc  = 256;
static constexpr int M_  = B_ * Nn;        // 50176
static constexpr int GH_ = 4;
static constexpr int GD_ = 128;
static constexpr int LD_ = 128;
static constexpr int HID_ = 1024;
static constexpr int TG_ = 256;            // 16*16 windows
static constexpr int T__ = 49;             // 7*7 tokens per window
static constexpr float SCALE_ = 0.17677669529663687f;  // 32^-0.5

__device__ __forceinline__ float toF(const bf16 v)  { return __bfloat162float(v); }
__device__ __forceinline__ float toF(const float v) { return v; }
__device__ __forceinline__ void st_out(float* p, float v) { *p = v; }
__device__ __forceinline__ void st_out(bf16* p, float v)  { *p = __float2bfloat16(v); }

// windowed row r = ((b*256 + g)*49 + t)  ->  flat row b*N + n
__device__ __forceinline__ int win_row_map(int r) {
  int b  = r / Nn;
  int rr = r - b * Nn;
  int g  = rr / T__;
  int t  = rr - g * T__;
  int gh = g >> 4, gw = g & 15;
  int i  = t / 7,  j  = t - i * 7;
  int n  = (gh * 7 + i) * Ww + gw * 7 + j;
  return b * Nn + n;
}

__global__ void guard_fill_kernel(float* out) {
  out[threadIdx.x + blockIdx.x * 256] = 1.0e6f;  // sentinel: workspace guard tripped
}

// ---------------- weight convert + transpose: Wt[n*K+k] = bf16(W[k*N+n]) ----------------
__global__ __launch_bounds__(256) void convert_w_kernel(const float* __restrict__ W,
                                                        bf16* __restrict__ Wt,
                                                        int K, int N) {
  int idx = blockIdx.x * 256 + threadIdx.x;
  if (idx >= N * K) return;
  int n = idx / K, k = idx - n * K;
  Wt[idx] = __float2bfloat16(W[(size_t)k * N + n]);
}

// ---------------- LayerNorm (one block per row of 256 channels) ----------------
template <typename T>
__global__ __launch_bounds__(256) void ln_kernel(const T* __restrict__ x,
                                                 const float* __restrict__ g,
                                                 const float* __restrict__ bta,
                                                 bf16* __restrict__ out) {
  const int row = blockIdx.x;
  const int tid = threadIdx.x;
  float v = toF(x[(size_t)row * Cc + tid]);
  float s = v, ss = v * v;
  #pragma unroll
  for (int off = 32; off > 0; off >>= 1) {
    s  += __shfl_down(s, off);
    ss += __shfl_down(ss, off);
  }
  __shared__ float rbuf[8];
  const int lane = tid & 63, wid = tid >> 6;
  if (lane == 0) { rbuf[wid] = s; rbuf[4 + wid] = ss; }
  __syncthreads();
  float ts  = rbuf[0] + rbuf[1] + rbuf[2] + rbuf[3];
  float tss = rbuf[4] + rbuf[5] + rbuf[6] + rbuf[7];
  float mean = ts * (1.0f / Cc);
  float var  = tss * (1.0f / Cc) - mean * mean;
  float r = rsqrtf(var + 1e-5f);
  float o = (v - mean) * r * g[tid] + bta[tid];
  out[(size_t)row * Cc + tid] = __float2bfloat16(o);
}

// ---------------- 7x7 average pool of xrn -> pooled (B,256,C) ----------------
__global__ __launch_bounds__(256) void pool_kernel(const bf16* __restrict__ xrn,
                                                   bf16* __restrict__ pooled) {
  const int c  = threadIdx.x;
  const int g  = blockIdx.x;   // gh*16+gw
  const int b  = blockIdx.y;
  const int gh = g >> 4, gw = g & 15;
  float s = 0.f;
  #pragma unroll
  for (int i = 0; i < 7; i++)
    for (int j = 0; j < 7; j++) {
      int n = (gh * 7 + i) * Ww + gw * 7 + j;
      s += toF(xrn[((size_t)b * Nn + n) * Cc + c]);
    }
  pooled[((size_t)b * TG_ + g) * Cc + c] = __float2bfloat16(s * (1.0f / 49.0f));
}

// ---------------- MFMA GEMM: out[M,N] = A[M,K](bf16) @ Wt[N,K](bf16,transposed) + bias ----------------
// 128x128 block tile, 4 waves in 2x2, each wave 64x64 via 4x4 mfma_f32_16x16x32_bf16.
// Requires M%128==0, N%128==0, K%32==0.
template <typename OutT, bool WIN_A, bool RES>
__global__ __launch_bounds__(256) void mfma_gemm_kernel(const bf16* __restrict__ A,
                                                        const bf16* __restrict__ Wt,
                                                        const float* __restrict__ bias,
                                                        const float* __restrict__ res,
                                                        OutT* __restrict__ out,
                                                        int M, int N, int K) {
  __shared__ __align__(16) bf16 As[128][40];  // +8 pad: 2-way banks on b128 frag reads
  __shared__ __align__(16) bf16 Bs[128][40];
  const int tid = threadIdx.x;
  const int bm = blockIdx.y * 128, bn = blockIdx.x * 128;
  const int lane = tid & 63, w = tid >> 6;
  const int wm = (w >> 1) * 64, wn = (w & 1) * 64;
  // staging: thread t loads 16 bf16 (32B) of row sr at col sc for both A and B
  const int sr = tid >> 1;
  const int sc = (tid & 1) * 16;
  const int arow = bm + sr;
  const int asrc = WIN_A ? win_row_map(arow) : arow;
  const bf16* Ag = A  + (size_t)asrc * K + sc;
  const bf16* Bg = Wt + (size_t)(bn + sr) * K + sc;

  f32x4 acc[4][4];
  #pragma unroll
  for (int i = 0; i < 4; i++)
    #pragma unroll
    for (int j = 0; j < 4; j++) acc[i][j] = (f32x4){0.f, 0.f, 0.f, 0.f};

  const int mrow = wm + (lane & 15);
  const int nrow = wn + (lane & 15);
  const int koct = (lane >> 4) * 8;

  for (int k0 = 0; k0 < K; k0 += 32) {
    uint4 a0 = *(const uint4*)(Ag + k0);
    uint4 a1 = *(const uint4*)(Ag + k0 + 8);
    uint4 b0 = *(const uint4*)(Bg + k0);
    uint4 b1 = *(const uint4*)(Bg + k0 + 8);
    *(uint4*)&As[sr][sc]     = a0;
    *(uint4*)&As[sr][sc + 8] = a1;
    *(uint4*)&Bs[sr][sc]     = b0;
    *(uint4*)&Bs[sr][sc + 8] = b1;
    __syncthreads();
    bf16x8 af[4], bfr[4];
    #pragma unroll
    for (int i = 0; i < 4; i++) af[i]  = *(const bf16x8*)&As[mrow + i * 16][koct];
    #pragma unroll
    for (int j = 0; j < 4; j++) bfr[j] = *(const bf16x8*)&Bs[nrow + j * 16][koct];
    #pragma unroll
    for (int i = 0; i < 4; i++)
      #pragma unroll
      for (int j = 0; j < 4; j++)
        acc[i][j] = __builtin_amdgcn_mfma_f32_16x16x32_bf16(af[i], bfr[j], acc[i][j], 0, 0, 0);
    __syncthreads();
  }

  // epilogue: C layout col=lane&15, row=(lane>>4)*4+reg  [m89-verified]
  const int r0  = (lane >> 4) * 4;
  const int cl  = lane & 15;
  #pragma unroll
  for (int j = 0; j < 4; j++) {
    const int col = bn + wn + j * 16 + cl;
    const float bv = bias[col];
    #pragma unroll
    for (int i = 0; i < 4; i++) {
      const int rowb = bm + wm + i * 16 + r0;
      #pragma unroll
      for (int r = 0; r < 4; r++) {
        size_t ro = (size_t)(rowb + r) * N + col;
        float v = acc[i][j][r] + bv;
        if (RES) v += res[ro];
        st_out(out + ro, v);
      }
    }
  }
}

// ---------------- global attention: single-pass exp, 2 queries/thread ----------------
// q (B*N,128) bf16 x kv (B*256,256) bf16 -> out bf16 (B*N,128)
__global__ __launch_bounds__(256) void gattn_kernel(const bf16* __restrict__ q,
                                                    const bf16* __restrict__ kv,
                                                    bf16* __restrict__ out) {
  __shared__ float ks[64 * 32];
  __shared__ float vs[64 * 32];
  const int tid = threadIdx.x;
  const int h = blockIdx.y, b = blockIdx.z;
  const bf16* kvb = kv + (size_t)b * TG_ * 256;
  const int n0 = blockIdx.x * 512 + tid;
  const int n1 = n0 + 256;
  const bool ok0 = n0 < Nn, ok1 = n1 < Nn;
  const size_t qo0 = ok0 ? (((size_t)b * Nn + n0) * GD_ + h * 32) : 0;
  const size_t qo1 = ok1 ? (((size_t)b * Nn + n1) * GD_ + h * 32) : 0;
  float qv0[32], qv1[32];
  #pragma unroll
  for (int d = 0; d < 32; d++) {
    qv0[d] = toF(q[qo0 + d]) * SCALE_;
    qv1[d] = toF(q[qo1 + d]) * SCALE_;
  }
  float l0 = 0.f, l1 = 0.f;
  float a0[32] = {}, a1[32] = {};
  for (int c0 = 0; c0 < 256; c0 += 64) {
    for (int idx = tid; idx < 64 * 32; idx += 256) {
      int m = idx >> 5, d = idx & 31;
      ks[idx] = toF(kvb[(size_t)(c0 + m) * 256 + h * 32 + d]);
      vs[idx] = toF(kvb[(size_t)(c0 + m) * 256 + 128 + h * 32 + d]);
    }
    __syncthreads();
    for (int m = 0; m < 64; m++) {
      const float* kr = ks + m * 32;
      const float* vr = vs + m * 32;
      float s0 = 0.f, s1 = 0.f;
      #pragma unroll
      for (int d = 0; d < 32; d++) {
        float kd = kr[d];
        s0 = fmaf(qv0[d], kd, s0);
        s1 = fmaf(qv1[d], kd, s1);
      }
      // scores here are O(0.1); exp without max-shift is exact (softmax shift-invariant).
      float p0 = __expf(fminf(s0, 60.f));
      float p1 = __expf(fminf(s1, 60.f));
      l0 += p0; l1 += p1;
      #pragma unroll
      for (int d = 0; d < 32; d++) {
        float vd = vr[d];
        a0[d] = fmaf(p0, vd, a0[d]);
        a1[d] = fmaf(p1, vd, a1[d]);
      }
    }
    __syncthreads();
  }
  if (ok0) {
    const float rl = 1.0f / l0;
    #pragma unroll
    for (int d = 0; d < 32; d++) out[qo0 + d] = __float2bfloat16(a0[d] * rl);
  }
  if (ok1) {
    const float rl = 1.0f / l1;
    #pragma unroll
    for (int d = 0; d < 32; d++) out[qo1 + d] = __float2bfloat16(a1[d] * rl);
  }
}

// ---------------- local window attention: one wave per (b, window, head) ----------------
__global__ __launch_bounds__(64) void lattn_kernel(const bf16* __restrict__ ql,
                                                   const bf16* __restrict__ kvl,
                                                   bf16* __restrict__ out) {
  __shared__ float ks[T__ * 32];
  __shared__ float vs[T__ * 32];
  const int tid = threadIdx.x;
  const int h = blockIdx.x, g = blockIdx.y, b = blockIdx.z;
  const size_t base = (((size_t)b * TG_ + g) * T__) * 256;
  for (int idx = tid; idx < T__ * 32; idx += 64) {
    int m = idx >> 5, d = idx & 31;
    ks[idx] = toF(kvl[base + (size_t)m * 256 + h * 32 + d]);
    vs[idx] = toF(kvl[base + (size_t)m * 256 + 128 + h * 32 + d]);
  }
  __syncthreads();
  if (tid < T__) {
    const size_t qoff = (((size_t)b * TG_ + g) * T__ + tid) * LD_ + h * 32;
    float qv[32];
    #pragma unroll
    for (int d = 0; d < 32; d++) qv[d] = toF(ql[qoff + d]) * SCALE_;
    float l = 0.f;
    float acc[32] = {};
    for (int m = 0; m < T__; m++) {
      const float* kr = ks + m * 32;
      const float* vr = vs + m * 32;
      float s = 0.f;
      #pragma unroll
      for (int d = 0; d < 32; d++) s = fmaf(qv[d], kr[d], s);
      float p = __expf(fminf(s, 60.f));
      l += p;
      #pragma unroll
      for (int d = 0; d < 32; d++) acc[d] = fmaf(p, vr[d], acc[d]);
    }
    const float rl = 1.0f / l;
    #pragma unroll
    for (int d = 0; d < 32; d++) out[qoff + d] = __float2bfloat16(acc[d] * rl);
  }
}

// ---------------- combine: xres = x + concat(gout, un-windowed lo) ----------------
__global__ __launch_bounds__(256) void combine_kernel(const float* __restrict__ x,
                                                      const bf16* __restrict__ gout,
                                                      const bf16* __restrict__ lo_w,
                                                      float* __restrict__ xres) {
  const int row = blockIdx.x;  // b*N + n
  const int c = threadIdx.x;
  float base = x[(size_t)row * Cc + c];
  float add;
  if (c < 128) {
    add = toF(gout[(size_t)row * GD_ + c]);
  } else {
    int b = row / Nn, n = row - b * Nn;
    int y = n / Ww, xx = n - y * Ww;
    int gh = y / 7, i = y - gh * 7;
    int gw = xx / 7, j = xx - gw * 7;
    size_t wrow = ((size_t)b * TG_ + gh * 16 + gw) * T__ + i * 7 + j;
    add = toF(lo_w[wrow * LD_ + (c - 128)]);
  }
  xres[(size_t)row * Cc + c] = base + add;
}

// ---------------- depthwise 3x3 conv (SAME) + bias + exact GELU, single batch ----------------
__global__ __launch_bounds__(256) void dwconv_gelu_kernel(const bf16* __restrict__ h1,
                                                          const float* __restrict__ w,
                                                          const float* __restrict__ bias,
                                                          bf16* __restrict__ h2) {
  const int n = blockIdx.x;            // n within one batch image
  const int y = n / Ww, x = n - y * Ww;
  const int c0 = threadIdx.x * 4;
  float acc[4] = {};
  #pragma unroll
  for (int di = -1; di <= 1; di++) {
    int yy = y + di;
    if (yy < 0 || yy >= Hh) continue;
    #pragma unroll
    for (int dj = -1; dj <= 1; dj++) {
      int xx = x + dj;
      if (xx < 0 || xx >= Ww) continue;
      size_t off = ((size_t)(yy * Ww + xx)) * HID_ + c0;
      #pragma unroll
      for (int u = 0; u < 4; u++)
        acc[u] = fmaf(toF(h1[off + u]), w[(c0 + u) * 9 + (di + 1) * 3 + (dj + 1)], acc[u]);
    }
  }
  size_t oo = (size_t)n * HID_ + c0;
  #pragma unroll
  for (int u = 0; u < 4; u++) {
    float v = acc[u] + bias[c0 + u];
    float gl = 0.5f * v * (1.0f + erff(v * 0.7071067811865475f));
    h2[oo + u] = __float2bfloat16(gl);
  }
}

extern "C" void kernel_launch(void* const* d_in, const int* in_sizes, int n_in,
                              void* d_out, int out_size, void* d_ws, size_t ws_size,
                              hipStream_t stream) {
  const float* x     = (const float*)d_in[0];
  const float* xrev  = (const float*)d_in[1];
  const float* g1    = (const float*)d_in[2];
  const float* b1    = (const float*)d_in[3];
  const float* g2    = (const float*)d_in[4];
  const float* b2    = (const float*)d_in[5];
  const float* Gq_w  = (const float*)d_in[6];
  const float* Gq_b  = (const float*)d_in[7];
  const float* Gkv_w = (const float*)d_in[8];
  const float* Gkv_b = (const float*)d_in[9];
  const float* Gp_w  = (const float*)d_in[10];
  const float* Gp_b  = (const float*)d_in[11];
  const float* Lq_w  = (const float*)d_in[12];
  const float* Lq_b  = (const float*)d_in[13];
  const float* Lkv_w = (const float*)d_in[14];
  const float* Lkv_b = (const float*)d_in[15];
  const float* Lp_w  = (const float*)d_in[16];
  const float* Lp_b  = (const float*)d_in[17];
  const float* fc1_w = (const float*)d_in[18];
  const float* fc1_b = (const float*)d_in[19];
  const float* dw_w  = (const float*)d_in[20];
  const float* dw_b  = (const float*)d_in[21];
  const float* fc2_w = (const float*)d_in[22];
  const float* fc2_b = (const float*)d_in[23];

  // ---- transposed bf16 weight arena (lives whole launch) ----
  const size_t E_GQ = 256 * 128, E_GKV = 256 * 256, E_GP = 128 * 128;
  const size_t E_LQ = 256 * 128, E_LKV = 256 * 256, E_LP = 128 * 128;
  const size_t E_F1 = 256 * 1024, E_F2 = 1024 * 256;
  char* ws = (char*)d_ws;
  bf16* Gq_t  = (bf16*)ws;
  bf16* Gkv_t = Gq_t  + E_GQ;
  bf16* Gp_t  = Gkv_t + E_GKV;
  bf16* Lq_t  = Gp_t  + E_GP;
  bf16* Lkv_t = Lq_t  + E_LQ;
  bf16* Lp_t  = Lkv_t + E_LKV;
  bf16* f1_t  = Lp_t  + E_LP;
  bf16* f2_t  = f1_t  + E_F1;
  const size_t WT_BYTES = 2 * (E_GQ + E_GKV + E_GP + E_LQ + E_LKV + E_LP + E_F1 + E_F2);

  // ---- activation arena (xres lives in d_out; in-place residual at step 15) ----
  const size_t SZ_ROW2 = (size_t)M_ * Cc * 2;        // 25,690,112  (256-col bf16)
  const size_t SZ_HALF = (size_t)M_ * 128 * 2;       // 12,845,056  (128-col bf16)
  const size_t SZ_POOL = (size_t)B_ * TG_ * Cc * 2;
  const size_t SZ_KVG  = (size_t)B_ * TG_ * 256 * 2;
  char* arena = ws + WT_BYTES;
  bf16* S1 = (bf16*)(arena);                          // xn -> kvl
  bf16* S2 = (bf16*)(arena + SZ_ROW2);                // xrn -> lo_w
  bf16* S3 = (bf16*)(arena + 2 * SZ_ROW2);            // q -> ql
  bf16* S4 = (bf16*)(arena + 2 * SZ_ROW2 + SZ_HALF);  // gattn -> lattn
  bf16* S5 = (bf16*)(arena + 2 * SZ_ROW2 + 2 * SZ_HALF);  // gout
  bf16* poolb = (bf16*)(arena + 2 * SZ_ROW2 + 3 * SZ_HALF);
  bf16* kvG   = (bf16*)(arena + 2 * SZ_ROW2 + 3 * SZ_HALF + SZ_POOL);
  const size_t ARENA_BYTES = 2 * SZ_ROW2 + 3 * SZ_HALF + SZ_POOL + SZ_KVG;
  // phase B (per-batch MLP) aliases the arena:
  bf16* xn2 = (bf16*)(arena);
  bf16* h1  = (bf16*)(arena + (size_t)Nn * Cc * 2);
  bf16* h2  = (bf16*)(arena + (size_t)Nn * Cc * 2 + (size_t)Nn * HID_ * 2);

  float* out  = (float*)d_out;
  float* xres = (float*)d_out;  // combine writes it; step-15 GEMM reads+overwrites in place
  if (ws_size < WT_BYTES + ARENA_BYTES) {  // ~92.5 MB
    guard_fill_kernel<<<16, 256, 0, stream>>>(out);
    return;
  }

  bf16* xn = S1;  bf16* xrn = S2;  bf16* qbuf = S3;  bf16* gattn = S4;  bf16* gout = S5;
  bf16* kvl = S1; bf16* lo_w = S2; bf16* qlb  = S3;  bf16* lattn = S4;

  // 0) convert+transpose weights to bf16 [N][K]
  convert_w_kernel<<<(int)((E_GQ  + 255) / 256), 256, 0, stream>>>(Gq_w,  Gq_t,  256, 128);
  convert_w_kernel<<<(int)((E_GKV + 255) / 256), 256, 0, stream>>>(Gkv_w, Gkv_t, 256, 256);
  convert_w_kernel<<<(int)((E_GP  + 255) / 256), 256, 0, stream>>>(Gp_w,  Gp_t,  128, 128);
  convert_w_kernel<<<(int)((E_LQ  + 255) / 256), 256, 0, stream>>>(Lq_w,  Lq_t,  256, 128);
  convert_w_kernel<<<(int)((E_LKV + 255) / 256), 256, 0, stream>>>(Lkv_w, Lkv_t, 256, 256);
  convert_w_kernel<<<(int)((E_LP  + 255) / 256), 256, 0, stream>>>(Lp_w,  Lp_t,  128, 128);
  convert_w_kernel<<<(int)((E_F1  + 255) / 256), 256, 0, stream>>>(fc1_w, f1_t,  256, 1024);
  convert_w_kernel<<<(int)((E_F2  + 255) / 256), 256, 0, stream>>>(fc2_w, f2_t,  1024, 256);

  // 1) LayerNorm both streams
  ln_kernel<float><<<M_, 256, 0, stream>>>(x, g1, b1, xn);
  ln_kernel<float><<<M_, 256, 0, stream>>>(xrev, g1, b1, xrn);
  // 2) 7x7 pool of xrn
  pool_kernel<<<dim3(TG_, B_), 256, 0, stream>>>(xrn, poolb);
  // 3) q = xn @ Gq_w + b
  mfma_gemm_kernel<bf16, false, false><<<dim3(1, M_ / 128), 256, 0, stream>>>(
      xn, Gq_t, Gq_b, nullptr, qbuf, M_, 128, 256);
  // 4) kv = pooled @ Gkv_w + b
  mfma_gemm_kernel<bf16, false, false><<<dim3(2, 8), 256, 0, stream>>>(
      poolb, Gkv_t, Gkv_b, nullptr, kvG, 1024, 256, 256);
  // 5) global attention
  gattn_kernel<<<dim3((Nn + 511) / 512, GH_, B_), 256, 0, stream>>>(qbuf, kvG, gattn);
  // 6) gout = gattn @ Gp_w + b
  mfma_gemm_kernel<bf16, false, false><<<dim3(1, M_ / 128), 256, 0, stream>>>(
      gattn, Gp_t, Gp_b, nullptr, gout, M_, 128, 128);
  // 7) ql = windows(xn) @ Lq_w + b
  mfma_gemm_kernel<bf16, true, false><<<dim3(1, M_ / 128), 256, 0, stream>>>(
      xn, Lq_t, Lq_b, nullptr, qlb, M_, 128, 256);
  // 8) kvl = windows(xrn) @ Lkv_w + b   (writes xn slot — dead after 7)
  mfma_gemm_kernel<bf16, true, false><<<dim3(2, M_ / 128), 256, 0, stream>>>(
      xrn, Lkv_t, Lkv_b, nullptr, kvl, M_, 256, 256);
  // 9) local attention
  lattn_kernel<<<dim3(4, TG_, B_), 64, 0, stream>>>(qlb, kvl, lattn);
  // 10) lo = lattn @ Lp_w + b   (windowed row order; writes xrn slot)
  mfma_gemm_kernel<bf16, false, false><<<dim3(1, M_ / 128), 256, 0, stream>>>(
      lattn, Lp_t, Lp_b, nullptr, lo_w, M_, 128, 128);
  // 11) xres(=d_out) = x + concat(gout, unwindow(lo))
  combine_kernel<<<M_, 256, 0, stream>>>(x, gout, lo_w, xres);
  // 12-15) MLP per batch
  for (int b = 0; b < B_; b++) {
    const float* xres_b = xres + (size_t)b * Nn * Cc;
    float* out_b = out + (size_t)b * Nn * Cc;
    ln_kernel<float><<<Nn, 256, 0, stream>>>(xres_b, g2, b2, xn2);
    mfma_gemm_kernel<bf16, false, false><<<dim3(8, Nn / 128), 256, 0, stream>>>(
        xn2, f1_t, fc1_b, nullptr, h1, Nn, 1024, 256);
    dwconv_gelu_kernel<<<Nn, 256, 0, stream>>>(h1, dw_w, dw_b, h2);
    mfma_gemm_kernel<float, false, true><<<dim3(2, Nn / 128), 256, 0, stream>>>(
        h2, f2_t, fc2_b, xres_b, out_b, Nn, 256, 1024);
  }
}

// Round 5
// 1165.635 us; speedup vs baseline: 2.4498x; 1.2154x over previous
//
#include <hip/hip_runtime.h>
#include <hip/hip_bf16.h>
#include <math.h>

typedef __hip_bfloat16 bf16;
typedef __attribute__((ext_vector_type(8))) short bf16x8;
typedef __attribute__((ext_vector_type(4))) float f32x4;

static constexpr int B_  = 4;
static constexpr int Hh  = 112, Ww = 112;
static constexpr int Nn  = Hh * Ww;        // 12544
static constexpr int Cc  = 256;
static constexpr int M_  = B_ * Nn;        // 50176
static constexpr int GH_ = 4;
static constexpr int GD_ = 128;
static constexpr int LD_ = 128;
static constexpr int HID_ = 1024;
static constexpr int TG_ = 256;            // 16*16 windows
static constexpr int T__ = 49;             // 7*7 tokens per window
static constexpr float SCALE_ = 0.17677669529663687f;  // 32^-0.5

__device__ __forceinline__ float toF(const bf16 v)  { return __bfloat162float(v); }
__device__ __forceinline__ float toF(const float v) { return v; }
__device__ __forceinline__ void st_out(float* p, float v) { *p = v; }
__device__ __forceinline__ void st_out(bf16* p, float v)  { *p = __float2bfloat16(v); }

// windowed row r = ((b*256 + g)*49 + t)  ->  flat row b*N + n
__device__ __forceinline__ int win_row_map(int r) {
  int b  = r / Nn;
  int rr = r - b * Nn;
  int g  = rr / T__;
  int t  = rr - g * T__;
  int gh = g >> 4, gw = g & 15;
  int i  = t / 7,  j  = t - i * 7;
  int n  = (gh * 7 + i) * Ww + gw * 7 + j;
  return b * Nn + n;
}

__global__ void guard_fill_kernel(float* out) {
  out[threadIdx.x + blockIdx.x * 256] = 1.0e6f;  // sentinel: workspace guard tripped
}

// ---------------- fused weight convert+transpose for all 8 weights ----------------
// wt arena is contiguous in segment order; Wt[n*K+k] = bf16(W[k*N+n]).
__global__ __launch_bounds__(256) void convert_all_kernel(
    const float* __restrict__ s0, const float* __restrict__ s1,
    const float* __restrict__ s2, const float* __restrict__ s3,
    const float* __restrict__ s4, const float* __restrict__ s5,
    const float* __restrict__ s6, const float* __restrict__ s7,
    bf16* __restrict__ wt) {
  int idx = blockIdx.x * 256 + threadIdx.x;   // grid sized exactly: 753664 = 2944*256
  const float* W; int K, N, base;
  if      (idx < 32768)  { W = s0; K = 256;  N = 128;  base = 0; }
  else if (idx < 98304)  { W = s1; K = 256;  N = 256;  base = 32768; }
  else if (idx < 114688) { W = s2; K = 128;  N = 128;  base = 98304; }
  else if (idx < 147456) { W = s3; K = 256;  N = 128;  base = 114688; }
  else if (idx < 212992) { W = s4; K = 256;  N = 256;  base = 147456; }
  else if (idx < 229376) { W = s5; K = 128;  N = 128;  base = 212992; }
  else if (idx < 491520) { W = s6; K = 256;  N = 1024; base = 229376; }
  else                   { W = s7; K = 1024; N = 256;  base = 491520; }
  int loc = idx - base;
  int n = loc / K, k = loc - n * K;
  wt[idx] = __float2bfloat16(W[(size_t)k * N + n]);
}

// ---------------- LayerNorm (one block per row of 256 channels) ----------------
template <typename T>
__global__ __launch_bounds__(256) void ln_kernel(const T* __restrict__ x,
                                                 const float* __restrict__ g,
                                                 const float* __restrict__ bta,
                                                 bf16* __restrict__ out) {
  const int row = blockIdx.x;
  const int tid = threadIdx.x;
  float v = toF(x[(size_t)row * Cc + tid]);
  float s = v, ss = v * v;
  #pragma unroll
  for (int off = 32; off > 0; off >>= 1) {
    s  += __shfl_down(s, off);
    ss += __shfl_down(ss, off);
  }
  __shared__ float rbuf[8];
  const int lane = tid & 63, wid = tid >> 6;
  if (lane == 0) { rbuf[wid] = s; rbuf[4 + wid] = ss; }
  __syncthreads();
  float ts  = rbuf[0] + rbuf[1] + rbuf[2] + rbuf[3];
  float tss = rbuf[4] + rbuf[5] + rbuf[6] + rbuf[7];
  float mean = ts * (1.0f / Cc);
  float var  = tss * (1.0f / Cc) - mean * mean;
  float r = rsqrtf(var + 1e-5f);
  float o = (v - mean) * r * g[tid] + bta[tid];
  out[(size_t)row * Cc + tid] = __float2bfloat16(o);
}

// ---------------- 7x7 average pool of xrn -> pooled (B,256,C) ----------------
__global__ __launch_bounds__(256) void pool_kernel(const bf16* __restrict__ xrn,
                                                   bf16* __restrict__ pooled) {
  const int c  = threadIdx.x;
  const int g  = blockIdx.x;   // gh*16+gw
  const int b  = blockIdx.y;
  const int gh = g >> 4, gw = g & 15;
  float s = 0.f;
  #pragma unroll
  for (int i = 0; i < 7; i++)
    for (int j = 0; j < 7; j++) {
      int n = (gh * 7 + i) * Ww + gw * 7 + j;
      s += toF(xrn[((size_t)b * Nn + n) * Cc + c]);
    }
  pooled[((size_t)b * TG_ + g) * Cc + c] = __float2bfloat16(s * (1.0f / 49.0f));
}

// ---------------- MFMA GEMM: out[M,N] = A[M,K](bf16) @ Wt[N,K](bf16,transposed) + bias ----------------
template <typename OutT, bool WIN_A, bool RES>
__global__ __launch_bounds__(256) void mfma_gemm_kernel(const bf16* __restrict__ A,
                                                        const bf16* __restrict__ Wt,
                                                        const float* __restrict__ bias,
                                                        const float* __restrict__ res,
                                                        OutT* __restrict__ out,
                                                        int M, int N, int K) {
  __shared__ __align__(16) bf16 As[128][40];
  __shared__ __align__(16) bf16 Bs[128][40];
  const int tid = threadIdx.x;
  const int bm = blockIdx.y * 128, bn = blockIdx.x * 128;
  const int lane = tid & 63, w = tid >> 6;
  const int wm = (w >> 1) * 64, wn = (w & 1) * 64;
  const int sr = tid >> 1;
  const int sc = (tid & 1) * 16;
  const int arow = bm + sr;
  const int asrc = WIN_A ? win_row_map(arow) : arow;
  const bf16* Ag = A  + (size_t)asrc * K + sc;
  const bf16* Bg = Wt + (size_t)(bn + sr) * K + sc;

  f32x4 acc[4][4];
  #pragma unroll
  for (int i = 0; i < 4; i++)
    #pragma unroll
    for (int j = 0; j < 4; j++) acc[i][j] = (f32x4){0.f, 0.f, 0.f, 0.f};

  const int mrow = wm + (lane & 15);
  const int nrow = wn + (lane & 15);
  const int koct = (lane >> 4) * 8;

  for (int k0 = 0; k0 < K; k0 += 32) {
    uint4 a0 = *(const uint4*)(Ag + k0);
    uint4 a1 = *(const uint4*)(Ag + k0 + 8);
    uint4 b0 = *(const uint4*)(Bg + k0);
    uint4 b1 = *(const uint4*)(Bg + k0 + 8);
    *(uint4*)&As[sr][sc]     = a0;
    *(uint4*)&As[sr][sc + 8] = a1;
    *(uint4*)&Bs[sr][sc]     = b0;
    *(uint4*)&Bs[sr][sc + 8] = b1;
    __syncthreads();
    bf16x8 af[4], bfr[4];
    #pragma unroll
    for (int i = 0; i < 4; i++) af[i]  = *(const bf16x8*)&As[mrow + i * 16][koct];
    #pragma unroll
    for (int j = 0; j < 4; j++) bfr[j] = *(const bf16x8*)&Bs[nrow + j * 16][koct];
    #pragma unroll
    for (int i = 0; i < 4; i++)
      #pragma unroll
      for (int j = 0; j < 4; j++)
        acc[i][j] = __builtin_amdgcn_mfma_f32_16x16x32_bf16(af[i], bfr[j], acc[i][j], 0, 0, 0);
    __syncthreads();
  }

  const int r0  = (lane >> 4) * 4;
  const int cl  = lane & 15;
  #pragma unroll
  for (int j = 0; j < 4; j++) {
    const int col = bn + wn + j * 16 + cl;
    const float bv = bias[col];
    #pragma unroll
    for (int i = 0; i < 4; i++) {
      const int rowb = bm + wm + i * 16 + r0;
      #pragma unroll
      for (int r = 0; r < 4; r++) {
        size_t ro = (size_t)(rowb + r) * N + col;
        float v = acc[i][j][r] + bv;
        if (RES) v += res[ro];
        st_out(out + ro, v);
      }
    }
  }
}

// ---------------- MFMA flash global attention ----------------
// Per block: 128 q-rows of one (b,h). K,V^T in LDS; Q frags from global;
// scores -> exp -> P (wave-local LDS) -> PV, all on matrix pipe.
__global__ __launch_bounds__(256) void gattn_kernel(const bf16* __restrict__ q,
                                                    const bf16* __restrict__ kv,
                                                    bf16* __restrict__ out) {
  __shared__ __align__(16) bf16 Ks[256][40];     // [key][d]   20.5 KB
  __shared__ __align__(16) bf16 Vt[32][264];     // [d][key]   16.9 KB
  __shared__ __align__(16) bf16 Ps[4][32][40];   // per-wave P 10.2 KB
  const int tid = threadIdx.x;
  const int lane = tid & 63, w = tid >> 6;
  const int h = blockIdx.y, b = blockIdx.z;
  const int n0 = blockIdx.x * 128;
  const int r16 = lane & 15, oct = (lane >> 4) * 8;
  const bf16* kvb = kv + (size_t)b * TG_ * 256;

  // stage K row-major + V transposed (256 threads, one key each)
  {
    const int key = tid;
    const bf16* kp = kvb + (size_t)key * 256 + h * 32;
    *(uint4*)&Ks[key][0]  = *(const uint4*)(kp);
    *(uint4*)&Ks[key][8]  = *(const uint4*)(kp + 8);
    *(uint4*)&Ks[key][16] = *(const uint4*)(kp + 16);
    *(uint4*)&Ks[key][24] = *(const uint4*)(kp + 24);
    union { uint4 u[4]; bf16 e[32]; } vv;
    vv.u[0] = *(const uint4*)(kp + 128);
    vv.u[1] = *(const uint4*)(kp + 136);
    vv.u[2] = *(const uint4*)(kp + 144);
    vv.u[3] = *(const uint4*)(kp + 152);
    #pragma unroll
    for (int d = 0; d < 32; d++) Vt[d][key] = vv.e[d];
  }
  // Q A-frags straight from global (2 row-tiles of 16 per wave)
  const size_t qbase0 = ((size_t)(b * Nn + n0 + w * 32 + r16)) * GD_ + h * 32 + oct;
  bf16x8 aq0 = *(const bf16x8*)(q + qbase0);
  bf16x8 aq1 = *(const bf16x8*)(q + qbase0 + (size_t)16 * GD_);
  __syncthreads();

  f32x4 rs0 = {0.f, 0.f, 0.f, 0.f}, rs1 = {0.f, 0.f, 0.f, 0.f};
  f32x4 ov[2][2];
  #pragma unroll
  for (int i = 0; i < 2; i++)
    #pragma unroll
    for (int dt = 0; dt < 2; dt++) ov[i][dt] = (f32x4){0.f, 0.f, 0.f, 0.f};

  for (int c0 = 0; c0 < 256; c0 += 32) {   // 32-key chunks
    #pragma unroll
    for (int t = 0; t < 2; t++) {
      bf16x8 bk = *(const bf16x8*)&Ks[c0 + t * 16 + r16][oct];
      f32x4 s0 = __builtin_amdgcn_mfma_f32_16x16x32_bf16(aq0, bk, (f32x4){0.f,0.f,0.f,0.f}, 0, 0, 0);
      f32x4 s1 = __builtin_amdgcn_mfma_f32_16x16x32_bf16(aq1, bk, (f32x4){0.f,0.f,0.f,0.f}, 0, 0, 0);
      const int prow = (lane >> 4) * 4;
      const int pcol = t * 16 + r16;
      #pragma unroll
      for (int r = 0; r < 4; r++) {
        bf16 pb0 = __float2bfloat16(__expf(s0[r] * SCALE_));
        bf16 pb1 = __float2bfloat16(__expf(s1[r] * SCALE_));
        rs0[r] += toF(pb0);       // sum the *rounded* P for exact normalization
        rs1[r] += toF(pb1);
        Ps[w][prow + r][pcol]      = pb0;
        Ps[w][16 + prow + r][pcol] = pb1;
      }
    }
    // PV: A = P (wave-local, no barrier needed), B = Vt
    bf16x8 ap0 = *(const bf16x8*)&Ps[w][r16][oct];
    bf16x8 ap1 = *(const bf16x8*)&Ps[w][16 + r16][oct];
    #pragma unroll
    for (int dt = 0; dt < 2; dt++) {
      bf16x8 bv = *(const bf16x8*)&Vt[dt * 16 + r16][c0 + oct];
      ov[0][dt] = __builtin_amdgcn_mfma_f32_16x16x32_bf16(ap0, bv, ov[0][dt], 0, 0, 0);
      ov[1][dt] = __builtin_amdgcn_mfma_f32_16x16x32_bf16(ap1, bv, ov[1][dt], 0, 0, 0);
    }
  }
  // row sums: reduce across lane&15
  #pragma unroll
  for (int off = 1; off < 16; off <<= 1) {
    #pragma unroll
    for (int r = 0; r < 4; r++) {
      rs0[r] += __shfl_xor(rs0[r], off);
      rs1[r] += __shfl_xor(rs1[r], off);
    }
  }
  const int orow0 = b * Nn + n0 + w * 32 + (lane >> 4) * 4;
  #pragma unroll
  for (int r = 0; r < 4; r++) {
    float inv0 = 1.0f / rs0[r];
    float inv1 = 1.0f / rs1[r];
    size_t ro0 = (size_t)(orow0 + r) * GD_ + h * 32;
    size_t ro1 = ro0 + (size_t)16 * GD_;
    #pragma unroll
    for (int dt = 0; dt < 2; dt++) {
      out[ro0 + dt * 16 + r16] = __float2bfloat16(ov[0][dt][r] * inv0);
      out[ro1 + dt * 16 + r16] = __float2bfloat16(ov[1][dt][r] * inv1);
    }
  }
}

// ---------------- local window attention: one wave per (b, window, head) ----------------
__global__ __launch_bounds__(64) void lattn_kernel(const bf16* __restrict__ ql,
                                                   const bf16* __restrict__ kvl,
                                                   bf16* __restrict__ out) {
  __shared__ float ks[T__ * 32];
  __shared__ float vs[T__ * 32];
  const int tid = threadIdx.x;
  const int h = blockIdx.x, g = blockIdx.y, b = blockIdx.z;
  const size_t base = (((size_t)b * TG_ + g) * T__) * 256;
  for (int idx = tid; idx < T__ * 32; idx += 64) {
    int m = idx >> 5, d = idx & 31;
    ks[idx] = toF(kvl[base + (size_t)m * 256 + h * 32 + d]);
    vs[idx] = toF(kvl[base + (size_t)m * 256 + 128 + h * 32 + d]);
  }
  __syncthreads();
  if (tid < T__) {
    const size_t qoff = (((size_t)b * TG_ + g) * T__ + tid) * LD_ + h * 32;
    float qv[32];
    #pragma unroll
    for (int d = 0; d < 32; d++) qv[d] = toF(ql[qoff + d]) * SCALE_;
    float l = 0.f;
    float acc[32] = {};
    for (int m = 0; m < T__; m++) {
      const float* kr = ks + m * 32;
      const float* vr = vs + m * 32;
      float s = 0.f;
      #pragma unroll
      for (int d = 0; d < 32; d++) s = fmaf(qv[d], kr[d], s);
      float p = __expf(fminf(s, 60.f));
      l += p;
      #pragma unroll
      for (int d = 0; d < 32; d++) acc[d] = fmaf(p, vr[d], acc[d]);
    }
    const float rl = 1.0f / l;
    #pragma unroll
    for (int d = 0; d < 32; d++) out[qoff + d] = __float2bfloat16(acc[d] * rl);
  }
}

// ---------------- combine + LN2 fused: xres = x + concat(gout, unwin(lo)); xn2 = LN(xres) ----------------
__global__ __launch_bounds__(256) void combine_ln_kernel(const float* __restrict__ x,
                                                         const bf16* __restrict__ gout,
                                                         const bf16* __restrict__ lo_w,
                                                         const float* __restrict__ g2,
                                                         const float* __restrict__ b2,
                                                         float* __restrict__ xres,
                                                         bf16* __restrict__ xn2) {
  const int row = blockIdx.x;  // b*N + n
  const int c = threadIdx.x;
  float add;
  if (c < 128) {
    add = toF(gout[(size_t)row * GD_ + c]);
  } else {
    int b = row / Nn, n = row - b * Nn;
    int y = n / Ww, xx = n - y * Ww;
    int gh = y / 7, i = y - gh * 7;
    int gw = xx / 7, j = xx - gw * 7;
    size_t wrow = ((size_t)b * TG_ + gh * 16 + gw) * T__ + i * 7 + j;
    add = toF(lo_w[wrow * LD_ + (c - 128)]);
  }
  float v = x[(size_t)row * Cc + c] + add;
  xres[(size_t)row * Cc + c] = v;
  // fused LayerNorm
  float s = v, ss = v * v;
  #pragma unroll
  for (int off = 32; off > 0; off >>= 1) {
    s  += __shfl_down(s, off);
    ss += __shfl_down(ss, off);
  }
  __shared__ float rbuf[8];
  const int lane = c & 63, wid = c >> 6;
  if (lane == 0) { rbuf[wid] = s; rbuf[4 + wid] = ss; }
  __syncthreads();
  float ts  = rbuf[0] + rbuf[1] + rbuf[2] + rbuf[3];
  float tss = rbuf[4] + rbuf[5] + rbuf[6] + rbuf[7];
  float mean = ts * (1.0f / Cc);
  float var  = tss * (1.0f / Cc) - mean * mean;
  float r = rsqrtf(var + 1e-5f);
  xn2[(size_t)row * Cc + c] = __float2bfloat16((v - mean) * r * g2[c] + b2[c]);
}

// ---------------- depthwise 3x3 conv (SAME) + bias + exact GELU, multi-image buffer ----------------
__global__ __launch_bounds__(256) void dwconv_gelu_kernel(const bf16* __restrict__ h1,
                                                          const float* __restrict__ w,
                                                          const float* __restrict__ bias,
                                                          bf16* __restrict__ h2) {
  const int sp = blockIdx.x;
  const int img = sp / Nn, n = sp - img * Nn;
  const int y = n / Ww, x = n - y * Ww;
  const int c0 = threadIdx.x * 4;
  const size_t ibase = (size_t)img * Nn * HID_;
  float acc[4] = {};
  #pragma unroll
  for (int di = -1; di <= 1; di++) {
    int yy = y + di;
    if (yy < 0 || yy >= Hh) continue;
    #pragma unroll
    for (int dj = -1; dj <= 1; dj++) {
      int xx = x + dj;
      if (xx < 0 || xx >= Ww) continue;
      size_t off = ibase + ((size_t)(yy * Ww + xx)) * HID_ + c0;
      #pragma unroll
      for (int u = 0; u < 4; u++)
        acc[u] = fmaf(toF(h1[off + u]), w[(c0 + u) * 9 + (di + 1) * 3 + (dj + 1)], acc[u]);
    }
  }
  size_t oo = (size_t)sp * HID_ + c0;
  #pragma unroll
  for (int u = 0; u < 4; u++) {
    float v = acc[u] + bias[c0 + u];
    float gl = 0.5f * v * (1.0f + erff(v * 0.7071067811865475f));
    h2[oo + u] = __float2bfloat16(gl);
  }
}

extern "C" void kernel_launch(void* const* d_in, const int* in_sizes, int n_in,
                              void* d_out, int out_size, void* d_ws, size_t ws_size,
                              hipStream_t stream) {
  const float* x     = (const float*)d_in[0];
  const float* xrev  = (const float*)d_in[1];
  const float* g1    = (const float*)d_in[2];
  const float* b1    = (const float*)d_in[3];
  const float* g2    = (const float*)d_in[4];
  const float* b2    = (const float*)d_in[5];
  const float* Gq_w  = (const float*)d_in[6];
  const float* Gq_b  = (const float*)d_in[7];
  const float* Gkv_w = (const float*)d_in[8];
  const float* Gkv_b = (const float*)d_in[9];
  const float* Gp_w  = (const float*)d_in[10];
  const float* Gp_b  = (const float*)d_in[11];
  const float* Lq_w  = (const float*)d_in[12];
  const float* Lq_b  = (const float*)d_in[13];
  const float* Lkv_w = (const float*)d_in[14];
  const float* Lkv_b = (const float*)d_in[15];
  const float* Lp_w  = (const float*)d_in[16];
  const float* Lp_b  = (const float*)d_in[17];
  const float* fc1_w = (const float*)d_in[18];
  const float* fc1_b = (const float*)d_in[19];
  const float* dw_w  = (const float*)d_in[20];
  const float* dw_b  = (const float*)d_in[21];
  const float* fc2_w = (const float*)d_in[22];
  const float* fc2_b = (const float*)d_in[23];

  // ---- transposed bf16 weight arena (contiguous, matches convert_all segments) ----
  const size_t E_GQ = 256 * 128, E_GKV = 256 * 256, E_GP = 128 * 128;
  const size_t E_LQ = 256 * 128, E_LKV = 256 * 256, E_LP = 128 * 128;
  const size_t E_F1 = 256 * 1024, E_F2 = 1024 * 256;
  char* ws = (char*)d_ws;
  bf16* Gq_t  = (bf16*)ws;
  bf16* Gkv_t = Gq_t  + E_GQ;
  bf16* Gp_t  = Gkv_t + E_GKV;
  bf16* Lq_t  = Gp_t  + E_GP;
  bf16* Lkv_t = Lq_t  + E_LQ;
  bf16* Lp_t  = Lkv_t + E_LKV;
  bf16* f1_t  = Lp_t  + E_LP;
  bf16* f2_t  = f1_t  + E_F1;
  const size_t WT_ELEMS = E_GQ + E_GKV + E_GP + E_LQ + E_LKV + E_LP + E_F1 + E_F2;  // 753664
  const size_t WT_BYTES = WT_ELEMS * 2;

  // ---- activation arena ----
  const size_t SZ_ROW2 = (size_t)M_ * Cc * 2;        // 25,690,112
  const size_t SZ_HALF = (size_t)M_ * 128 * 2;       // 12,845,056
  const size_t SZ_POOL = (size_t)B_ * TG_ * Cc * 2;
  const size_t SZ_KVG  = (size_t)B_ * TG_ * 256 * 2;
  const size_t SZ_H    = (size_t)(2 * Nn) * HID_ * 2;  // 51,380,224 per half
  char* arena = ws + WT_BYTES;
  bf16* S1 = (bf16*)(arena);                              // xn -> kvl -> xn2
  bf16* S2 = (bf16*)(arena + SZ_ROW2);                    // xrn -> lo_w
  bf16* S3 = (bf16*)(arena + 2 * SZ_ROW2);                // q -> ql
  bf16* S4 = (bf16*)(arena + 2 * SZ_ROW2 + SZ_HALF);      // gattn -> lattn
  bf16* S5 = (bf16*)(arena + 2 * SZ_ROW2 + 2 * SZ_HALF);  // gout
  bf16* poolb = (bf16*)(arena + 2 * SZ_ROW2 + 3 * SZ_HALF);
  bf16* kvG   = (bf16*)(arena + 2 * SZ_ROW2 + 3 * SZ_HALF + SZ_POOL);
  const size_t ARENA_A = 2 * SZ_ROW2 + 3 * SZ_HALF + SZ_POOL + SZ_KVG;  // ~91.0 MB
  // phase B (per-half MLP): xn2 keeps S1; h1/h2 overlay the dead S2..kvG region
  bf16* xn2 = S1;
  bf16* h1  = (bf16*)(arena + SZ_ROW2);
  bf16* h2  = (bf16*)(arena + SZ_ROW2 + SZ_H);
  const size_t ARENA_B = SZ_ROW2 + 2 * SZ_H;  // ~128.5 MB

  float* out  = (float*)d_out;
  float* xres = (float*)d_out;  // combine writes; final GEMM does in-place residual
  const size_t NEED = WT_BYTES + (ARENA_A > ARENA_B ? ARENA_A : ARENA_B);  // ~130 MB
  if (ws_size < NEED) {
    guard_fill_kernel<<<16, 256, 0, stream>>>(out);
    return;
  }

  bf16* xn = S1;  bf16* xrn = S2;  bf16* qbuf = S3;  bf16* gattn = S4;  bf16* gout = S5;
  bf16* kvl = S1; bf16* lo_w = S2; bf16* qlb  = S3;  bf16* lattn = S4;

  // 0) all weights -> bf16 transposed, one kernel
  convert_all_kernel<<<2944, 256, 0, stream>>>(Gq_w, Gkv_w, Gp_w, Lq_w, Lkv_w, Lp_w,
                                               fc1_w, fc2_w, (bf16*)ws);
  // 1) LayerNorm both streams
  ln_kernel<float><<<M_, 256, 0, stream>>>(x, g1, b1, xn);
  ln_kernel<float><<<M_, 256, 0, stream>>>(xrev, g1, b1, xrn);
  // 2) 7x7 pool of xrn
  pool_kernel<<<dim3(TG_, B_), 256, 0, stream>>>(xrn, poolb);
  // 3) q = xn @ Gq_w + b
  mfma_gemm_kernel<bf16, false, false><<<dim3(1, M_ / 128), 256, 0, stream>>>(
      xn, Gq_t, Gq_b, nullptr, qbuf, M_, 128, 256);
  // 4) kv = pooled @ Gkv_w + b
  mfma_gemm_kernel<bf16, false, false><<<dim3(2, 8), 256, 0, stream>>>(
      poolb, Gkv_t, Gkv_b, nullptr, kvG, 1024, 256, 256);
  // 5) global attention (MFMA flash)
  gattn_kernel<<<dim3(Nn / 128, GH_, B_), 256, 0, stream>>>(qbuf, kvG, gattn);
  // 6) gout = gattn @ Gp_w + b
  mfma_gemm_kernel<bf16, false, false><<<dim3(1, M_ / 128), 256, 0, stream>>>(
      gattn, Gp_t, Gp_b, nullptr, gout, M_, 128, 128);
  // 7) ql = windows(xn) @ Lq_w + b
  mfma_gemm_kernel<bf16, true, false><<<dim3(1, M_ / 128), 256, 0, stream>>>(
      xn, Lq_t, Lq_b, nullptr, qlb, M_, 128, 256);
  // 8) kvl = windows(xrn) @ Lkv_w + b  (overwrites xn slot — dead)
  mfma_gemm_kernel<bf16, true, false><<<dim3(2, M_ / 128), 256, 0, stream>>>(
      xrn, Lkv_t, Lkv_b, nullptr, kvl, M_, 256, 256);
  // 9) local attention
  lattn_kernel<<<dim3(4, TG_, B_), 64, 0, stream>>>(qlb, kvl, lattn);
  // 10) lo = lattn @ Lp_w + b  (windowed order; overwrites xrn slot)
  mfma_gemm_kernel<bf16, false, false><<<dim3(1, M_ / 128), 256, 0, stream>>>(
      lattn, Lp_t, Lp_b, nullptr, lo_w, M_, 128, 128);
  // 11) xres(=d_out) = x + concat(gout, unwin(lo)); xn2 = LN2(xres)  [fused]
  combine_ln_kernel<<<M_, 256, 0, stream>>>(x, gout, lo_w, g2, b2, xres, xn2);
  // 12-14) MLP in two halves (2 images each)
  for (int half = 0; half < 2; half++) {
    const size_t r0 = (size_t)half * 2 * Nn;
    mfma_gemm_kernel<bf16, false, false><<<dim3(8, (2 * Nn) / 128), 256, 0, stream>>>(
        xn2 + r0 * Cc, f1_t, fc1_b, nullptr, h1, 2 * Nn, 1024, 256);
    dwconv_gelu_kernel<<<2 * Nn, 256, 0, stream>>>(h1, dw_w, dw_b, h2);
    mfma_gemm_kernel<float, false, true><<<dim3(2, (2 * Nn) / 128), 256, 0, stream>>>(
        h2, f2_t, fc2_b, xres + r0 * Cc, out + r0 * Cc, 2 * Nn, 256, 1024);
  }
}

// Round 6
// 653.515 us; speedup vs baseline: 4.3695x; 1.7836x over previous
//
#include <hip/hip_runtime.h>
#include <hip/hip_bf16.h>
#include <math.h>

typedef __hip_bfloat16 bf16;
typedef __attribute__((ext_vector_type(8))) short bf16x8;
typedef __attribute__((ext_vector_type(4))) float f32x4;

static constexpr int B_  = 4;
static constexpr int Hh  = 112, Ww = 112;
static constexpr int Nn  = Hh * Ww;        // 12544
static constexpr int Cc  = 256;
static constexpr int M_  = B_ * Nn;        // 50176
static constexpr int GH_ = 4;
static constexpr int GD_ = 128;
static constexpr int LD_ = 128;
static constexpr int HID_ = 1024;
static constexpr int TG_ = 256;            // 16*16 windows
static constexpr int T__ = 49;             // 7*7 tokens per window
static constexpr float SCALE_ = 0.17677669529663687f;  // 32^-0.5

__device__ __forceinline__ float toF(const bf16 v)  { return __bfloat162float(v); }
__device__ __forceinline__ float toF(const float v) { return v; }
__device__ __forceinline__ void st_out(float* p, float v) { *p = v; }
__device__ __forceinline__ void st_out(bf16* p, float v)  { *p = __float2bfloat16(v); }

// windowed row r = ((b*256 + g)*49 + t)  ->  flat row b*N + n
__device__ __forceinline__ int win_row_map(int r) {
  int b  = r / Nn;
  int rr = r - b * Nn;
  int g  = rr / T__;
  int t  = rr - g * T__;
  int gh = g >> 4, gw = g & 15;
  int i  = t / 7,  j  = t - i * 7;
  int n  = (gh * 7 + i) * Ww + gw * 7 + j;
  return b * Nn + n;
}

__global__ void guard_fill_kernel(float* out) {
  out[threadIdx.x + blockIdx.x * 256] = 1.0e6f;  // sentinel: workspace guard tripped
}

// ---------------- fused weight convert+transpose for all 8 weights ----------------
__global__ __launch_bounds__(256) void convert_all_kernel(
    const float* __restrict__ s0, const float* __restrict__ s1,
    const float* __restrict__ s2, const float* __restrict__ s3,
    const float* __restrict__ s4, const float* __restrict__ s5,
    const float* __restrict__ s6, const float* __restrict__ s7,
    bf16* __restrict__ wt) {
  int idx = blockIdx.x * 256 + threadIdx.x;   // grid sized exactly: 753664 = 2944*256
  const float* W; int K, N, base;
  if      (idx < 32768)  { W = s0; K = 256;  N = 128;  base = 0; }
  else if (idx < 98304)  { W = s1; K = 256;  N = 256;  base = 32768; }
  else if (idx < 114688) { W = s2; K = 128;  N = 128;  base = 98304; }
  else if (idx < 147456) { W = s3; K = 256;  N = 128;  base = 114688; }
  else if (idx < 212992) { W = s4; K = 256;  N = 256;  base = 147456; }
  else if (idx < 229376) { W = s5; K = 128;  N = 128;  base = 212992; }
  else if (idx < 491520) { W = s6; K = 256;  N = 1024; base = 229376; }
  else                   { W = s7; K = 1024; N = 256;  base = 491520; }
  int loc = idx - base;
  int n = loc / K, k = loc - n * K;
  wt[idx] = __float2bfloat16(W[(size_t)k * N + n]);
}

// ---------------- LayerNorm (one block per row of 256 channels) ----------------
template <typename T>
__global__ __launch_bounds__(256) void ln_kernel(const T* __restrict__ x,
                                                 const float* __restrict__ g,
                                                 const float* __restrict__ bta,
                                                 bf16* __restrict__ out) {
  const int row = blockIdx.x;
  const int tid = threadIdx.x;
  float v = toF(x[(size_t)row * Cc + tid]);
  float s = v, ss = v * v;
  #pragma unroll
  for (int off = 32; off > 0; off >>= 1) {
    s  += __shfl_down(s, off);
    ss += __shfl_down(ss, off);
  }
  __shared__ float rbuf[8];
  const int lane = tid & 63, wid = tid >> 6;
  if (lane == 0) { rbuf[wid] = s; rbuf[4 + wid] = ss; }
  __syncthreads();
  float ts  = rbuf[0] + rbuf[1] + rbuf[2] + rbuf[3];
  float tss = rbuf[4] + rbuf[5] + rbuf[6] + rbuf[7];
  float mean = ts * (1.0f / Cc);
  float var  = tss * (1.0f / Cc) - mean * mean;
  float r = rsqrtf(var + 1e-5f);
  float o = (v - mean) * r * g[tid] + bta[tid];
  out[(size_t)row * Cc + tid] = __float2bfloat16(o);
}

// ---------------- 7x7 average pool of xrn -> pooled (B,256,C) ----------------
__global__ __launch_bounds__(256) void pool_kernel(const bf16* __restrict__ xrn,
                                                   bf16* __restrict__ pooled) {
  const int c  = threadIdx.x;
  const int g  = blockIdx.x;   // gh*16+gw
  const int b  = blockIdx.y;
  const int gh = g >> 4, gw = g & 15;
  float s = 0.f;
  #pragma unroll
  for (int i = 0; i < 7; i++)
    for (int j = 0; j < 7; j++) {
      int n = (gh * 7 + i) * Ww + gw * 7 + j;
      s += toF(xrn[((size_t)b * Nn + n) * Cc + c]);
    }
  pooled[((size_t)b * TG_ + g) * Cc + c] = __float2bfloat16(s * (1.0f / 49.0f));
}

// ---------------- MFMA GEMM: out[M,N] = A[M,K](bf16) @ Wt[N,K](bf16,transposed) + bias ----------------
template <typename OutT, bool WIN_A, bool RES>
__global__ __launch_bounds__(256) void mfma_gemm_kernel(const bf16* __restrict__ A,
                                                        const bf16* __restrict__ Wt,
                                                        const float* __restrict__ bias,
                                                        const float* __restrict__ res,
                                                        OutT* __restrict__ out,
                                                        int M, int N, int K) {
  __shared__ __align__(16) bf16 As[128][40];
  __shared__ __align__(16) bf16 Bs[128][40];
  const int tid = threadIdx.x;
  const int bm = blockIdx.y * 128, bn = blockIdx.x * 128;
  const int lane = tid & 63, w = tid >> 6;
  const int wm = (w >> 1) * 64, wn = (w & 1) * 64;
  const int sr = tid >> 1;
  const int sc = (tid & 1) * 16;
  const int arow = bm + sr;
  const int asrc = WIN_A ? win_row_map(arow) : arow;
  const bf16* Ag = A  + (size_t)asrc * K + sc;
  const bf16* Bg = Wt + (size_t)(bn + sr) * K + sc;

  f32x4 acc[4][4];
  #pragma unroll
  for (int i = 0; i < 4; i++)
    #pragma unroll
    for (int j = 0; j < 4; j++) acc[i][j] = (f32x4){0.f, 0.f, 0.f, 0.f};

  const int mrow = wm + (lane & 15);
  const int nrow = wn + (lane & 15);
  const int koct = (lane >> 4) * 8;

  for (int k0 = 0; k0 < K; k0 += 32) {
    uint4 a0 = *(const uint4*)(Ag + k0);
    uint4 a1 = *(const uint4*)(Ag + k0 + 8);
    uint4 b0 = *(const uint4*)(Bg + k0);
    uint4 b1 = *(const uint4*)(Bg + k0 + 8);
    *(uint4*)&As[sr][sc]     = a0;
    *(uint4*)&As[sr][sc + 8] = a1;
    *(uint4*)&Bs[sr][sc]     = b0;
    *(uint4*)&Bs[sr][sc + 8] = b1;
    __syncthreads();
    bf16x8 af[4], bfr[4];
    #pragma unroll
    for (int i = 0; i < 4; i++) af[i]  = *(const bf16x8*)&As[mrow + i * 16][koct];
    #pragma unroll
    for (int j = 0; j < 4; j++) bfr[j] = *(const bf16x8*)&Bs[nrow + j * 16][koct];
    #pragma unroll
    for (int i = 0; i < 4; i++)
      #pragma unroll
      for (int j = 0; j < 4; j++)
        acc[i][j] = __builtin_amdgcn_mfma_f32_16x16x32_bf16(af[i], bfr[j], acc[i][j], 0, 0, 0);
    __syncthreads();
  }

  const int r0  = (lane >> 4) * 4;
  const int cl  = lane & 15;
  #pragma unroll
  for (int j = 0; j < 4; j++) {
    const int col = bn + wn + j * 16 + cl;
    const float bv = bias[col];
    #pragma unroll
    for (int i = 0; i < 4; i++) {
      const int rowb = bm + wm + i * 16 + r0;
      #pragma unroll
      for (int r = 0; r < 4; r++) {
        size_t ro = (size_t)(rowb + r) * N + col;
        float v = acc[i][j][r] + bv;
        if (RES) v += res[ro];
        st_out(out + ro, v);
      }
    }
  }
}

// ---------------- MFMA flash global attention ----------------
__global__ __launch_bounds__(256) void gattn_kernel(const bf16* __restrict__ q,
                                                    const bf16* __restrict__ kv,
                                                    bf16* __restrict__ out) {
  __shared__ __align__(16) bf16 Ks[256][40];
  __shared__ __align__(16) bf16 Vt[32][264];
  __shared__ __align__(16) bf16 Ps[4][32][40];
  const int tid = threadIdx.x;
  const int lane = tid & 63, w = tid >> 6;
  const int h = blockIdx.y, b = blockIdx.z;
  const int n0 = blockIdx.x * 128;
  const int r16 = lane & 15, oct = (lane >> 4) * 8;
  const bf16* kvb = kv + (size_t)b * TG_ * 256;

  {
    const int key = tid;
    const bf16* kp = kvb + (size_t)key * 256 + h * 32;
    *(uint4*)&Ks[key][0]  = *(const uint4*)(kp);
    *(uint4*)&Ks[key][8]  = *(const uint4*)(kp + 8);
    *(uint4*)&Ks[key][16] = *(const uint4*)(kp + 16);
    *(uint4*)&Ks[key][24] = *(const uint4*)(kp + 24);
    union { uint4 u[4]; bf16 e[32]; } vv;
    vv.u[0] = *(const uint4*)(kp + 128);
    vv.u[1] = *(const uint4*)(kp + 136);
    vv.u[2] = *(const uint4*)(kp + 144);
    vv.u[3] = *(const uint4*)(kp + 152);
    #pragma unroll
    for (int d = 0; d < 32; d++) Vt[d][key] = vv.e[d];
  }
  const size_t qbase0 = ((size_t)(b * Nn + n0 + w * 32 + r16)) * GD_ + h * 32 + oct;
  bf16x8 aq0 = *(const bf16x8*)(q + qbase0);
  bf16x8 aq1 = *(const bf16x8*)(q + qbase0 + (size_t)16 * GD_);
  __syncthreads();

  f32x4 rs0 = {0.f, 0.f, 0.f, 0.f}, rs1 = {0.f, 0.f, 0.f, 0.f};
  f32x4 ov[2][2];
  #pragma unroll
  for (int i = 0; i < 2; i++)
    #pragma unroll
    for (int dt = 0; dt < 2; dt++) ov[i][dt] = (f32x4){0.f, 0.f, 0.f, 0.f};

  for (int c0 = 0; c0 < 256; c0 += 32) {
    #pragma unroll
    for (int t = 0; t < 2; t++) {
      bf16x8 bk = *(const bf16x8*)&Ks[c0 + t * 16 + r16][oct];
      f32x4 s0 = __builtin_amdgcn_mfma_f32_16x16x32_bf16(aq0, bk, (f32x4){0.f,0.f,0.f,0.f}, 0, 0, 0);
      f32x4 s1 = __builtin_amdgcn_mfma_f32_16x16x32_bf16(aq1, bk, (f32x4){0.f,0.f,0.f,0.f}, 0, 0, 0);
      const int prow = (lane >> 4) * 4;
      const int pcol = t * 16 + r16;
      #pragma unroll
      for (int r = 0; r < 4; r++) {
        bf16 pb0 = __float2bfloat16(__expf(s0[r] * SCALE_));
        bf16 pb1 = __float2bfloat16(__expf(s1[r] * SCALE_));
        rs0[r] += toF(pb0);
        rs1[r] += toF(pb1);
        Ps[w][prow + r][pcol]      = pb0;
        Ps[w][16 + prow + r][pcol] = pb1;
      }
    }
    bf16x8 ap0 = *(const bf16x8*)&Ps[w][r16][oct];
    bf16x8 ap1 = *(const bf16x8*)&Ps[w][16 + r16][oct];
    #pragma unroll
    for (int dt = 0; dt < 2; dt++) {
      bf16x8 bv = *(const bf16x8*)&Vt[dt * 16 + r16][c0 + oct];
      ov[0][dt] = __builtin_amdgcn_mfma_f32_16x16x32_bf16(ap0, bv, ov[0][dt], 0, 0, 0);
      ov[1][dt] = __builtin_amdgcn_mfma_f32_16x16x32_bf16(ap1, bv, ov[1][dt], 0, 0, 0);
    }
  }
  #pragma unroll
  for (int off = 1; off < 16; off <<= 1) {
    #pragma unroll
    for (int r = 0; r < 4; r++) {
      rs0[r] += __shfl_xor(rs0[r], off);
      rs1[r] += __shfl_xor(rs1[r], off);
    }
  }
  const int orow0 = b * Nn + n0 + w * 32 + (lane >> 4) * 4;
  #pragma unroll
  for (int r = 0; r < 4; r++) {
    float inv0 = 1.0f / rs0[r];
    float inv1 = 1.0f / rs1[r];
    size_t ro0 = (size_t)(orow0 + r) * GD_ + h * 32;
    size_t ro1 = ro0 + (size_t)16 * GD_;
    #pragma unroll
    for (int dt = 0; dt < 2; dt++) {
      out[ro0 + dt * 16 + r16] = __float2bfloat16(ov[0][dt][r] * inv0);
      out[ro1 + dt * 16 + r16] = __float2bfloat16(ov[1][dt][r] * inv1);
    }
  }
}

// ---------------- local window attention: one wave per (b, window, head) ----------------
__global__ __launch_bounds__(64) void lattn_kernel(const bf16* __restrict__ ql,
                                                   const bf16* __restrict__ kvl,
                                                   bf16* __restrict__ out) {
  __shared__ float ks[T__ * 32];
  __shared__ float vs[T__ * 32];
  const int tid = threadIdx.x;
  const int h = blockIdx.x, g = blockIdx.y, b = blockIdx.z;
  const size_t base = (((size_t)b * TG_ + g) * T__) * 256;
  for (int idx = tid; idx < T__ * 32; idx += 64) {
    int m = idx >> 5, d = idx & 31;
    ks[idx] = toF(kvl[base + (size_t)m * 256 + h * 32 + d]);
    vs[idx] = toF(kvl[base + (size_t)m * 256 + 128 + h * 32 + d]);
  }
  __syncthreads();
  if (tid < T__) {
    const size_t qoff = (((size_t)b * TG_ + g) * T__ + tid) * LD_ + h * 32;
    float qv[32];
    #pragma unroll
    for (int d = 0; d < 32; d++) qv[d] = toF(ql[qoff + d]) * SCALE_;
    float l = 0.f;
    float acc[32] = {};
    for (int m = 0; m < T__; m++) {
      const float* kr = ks + m * 32;
      const float* vr = vs + m * 32;
      float s = 0.f;
      #pragma unroll
      for (int d = 0; d < 32; d++) s = fmaf(qv[d], kr[d], s);
      float p = __expf(fminf(s, 60.f));
      l += p;
      #pragma unroll
      for (int d = 0; d < 32; d++) acc[d] = fmaf(p, vr[d], acc[d]);
    }
    const float rl = 1.0f / l;
    #pragma unroll
    for (int d = 0; d < 32; d++) out[qoff + d] = __float2bfloat16(acc[d] * rl);
  }
}

// ---------------- combine + LN2 fused ----------------
__global__ __launch_bounds__(256) void combine_ln_kernel(const float* __restrict__ x,
                                                         const bf16* __restrict__ gout,
                                                         const bf16* __restrict__ lo_w,
                                                         const float* __restrict__ g2,
                                                         const float* __restrict__ b2,
                                                         float* __restrict__ xres,
                                                         bf16* __restrict__ xn2) {
  const int row = blockIdx.x;  // b*N + n
  const int c = threadIdx.x;
  float add;
  if (c < 128) {
    add = toF(gout[(size_t)row * GD_ + c]);
  } else {
    int b = row / Nn, n = row - b * Nn;
    int y = n / Ww, xx = n - y * Ww;
    int gh = y / 7, i = y - gh * 7;
    int gw = xx / 7, j = xx - gw * 7;
    size_t wrow = ((size_t)b * TG_ + gh * 16 + gw) * T__ + i * 7 + j;
    add = toF(lo_w[wrow * LD_ + (c - 128)]);
  }
  float v = x[(size_t)row * Cc + c] + add;
  xres[(size_t)row * Cc + c] = v;
  float s = v, ss = v * v;
  #pragma unroll
  for (int off = 32; off > 0; off >>= 1) {
    s  += __shfl_down(s, off);
    ss += __shfl_down(ss, off);
  }
  __shared__ float rbuf[8];
  const int lane = c & 63, wid = c >> 6;
  if (lane == 0) { rbuf[wid] = s; rbuf[4 + wid] = ss; }
  __syncthreads();
  float ts  = rbuf[0] + rbuf[1] + rbuf[2] + rbuf[3];
  float tss = rbuf[4] + rbuf[5] + rbuf[6] + rbuf[7];
  float mean = ts * (1.0f / Cc);
  float var  = tss * (1.0f / Cc) - mean * mean;
  float r = rsqrtf(var + 1e-5f);
  xn2[(size_t)row * Cc + c] = __float2bfloat16((v - mean) * r * g2[c] + b2[c]);
}

// ---------------- depthwise 3x3 conv + bias + exact GELU: sliding-window row walker ----------------
// block = 256 threads x 4 channels; one (img, y, 28-wide x-tile) per block.
// Per x-step: 3 new 8B loads + 36 FMA + 4 GELU + 8B store (vs 36 scalar loads before).
__global__ __launch_bounds__(256) void dwconv_gelu_kernel(const bf16* __restrict__ h1,
                                                          const float* __restrict__ w,
                                                          const float* __restrict__ bias,
                                                          bf16* __restrict__ h2) {
  const int tid = threadIdx.x;
  const int c0 = tid * 4;
  const int img = blockIdx.z, y = blockIdx.y;
  const int xt = blockIdx.x * 28;
  const size_t ibase = (size_t)img * Nn * HID_;

  float wreg[9][4], breg[4];
  #pragma unroll
  for (int u = 0; u < 4; u++) {
    breg[u] = bias[c0 + u];
    #pragma unroll
    for (int t = 0; t < 9; t++) wreg[t][u] = w[(c0 + u) * 9 + t];
  }

  const bf16* rowp[3];
  bool rok[3];
  #pragma unroll
  for (int r = 0; r < 3; r++) {
    int yy = y - 1 + r;
    rok[r] = (yy >= 0 && yy < Hh);
    rowp[r] = h1 + ibase + (size_t)(rok[r] ? yy : 0) * Ww * HID_ + c0;
  }

  float wa[3][4], wb[3][4], wc[3][4];
  union U4 { ushort2 u2[2]; bf16 e[4]; };
  auto loadcol = [&](int xcol, float v[3][4]) {
    if (xcol < 0 || xcol >= Ww) {
      #pragma unroll
      for (int r = 0; r < 3; r++)
        #pragma unroll
        for (int u = 0; u < 4; u++) v[r][u] = 0.f;
      return;
    }
    #pragma unroll
    for (int r = 0; r < 3; r++) {
      if (rok[r]) {
        U4 raw;
        *(uint2*)&raw = *(const uint2*)(rowp[r] + (size_t)xcol * HID_);
        #pragma unroll
        for (int u = 0; u < 4; u++) v[r][u] = toF(raw.e[u]);
      } else {
        #pragma unroll
        for (int u = 0; u < 4; u++) v[r][u] = 0.f;
      }
    }
  };
  loadcol(xt - 1, wa);
  loadcol(xt, wb);

  for (int xx = 0; xx < 28; xx++) {
    const int x = xt + xx;
    loadcol(x + 1, wc);
    bf16 res[4];
    #pragma unroll
    for (int u = 0; u < 4; u++) {
      float a = breg[u];
      a = fmaf(wa[0][u], wreg[0][u], a);
      a = fmaf(wb[0][u], wreg[1][u], a);
      a = fmaf(wc[0][u], wreg[2][u], a);
      a = fmaf(wa[1][u], wreg[3][u], a);
      a = fmaf(wb[1][u], wreg[4][u], a);
      a = fmaf(wc[1][u], wreg[5][u], a);
      a = fmaf(wa[2][u], wreg[6][u], a);
      a = fmaf(wb[2][u], wreg[7][u], a);
      a = fmaf(wc[2][u], wreg[8][u], a);
      float gl = 0.5f * a * (1.0f + erff(a * 0.7071067811865475f));
      res[u] = __float2bfloat16(gl);
    }
    *(uint2*)(h2 + ibase + (size_t)(y * Ww + x) * HID_ + c0) = *(uint2*)res;
    #pragma unroll
    for (int r = 0; r < 3; r++)
      #pragma unroll
      for (int u = 0; u < 4; u++) { wa[r][u] = wb[r][u]; wb[r][u] = wc[r][u]; }
  }
}

extern "C" void kernel_launch(void* const* d_in, const int* in_sizes, int n_in,
                              void* d_out, int out_size, void* d_ws, size_t ws_size,
                              hipStream_t stream) {
  const float* x     = (const float*)d_in[0];
  const float* xrev  = (const float*)d_in[1];
  const float* g1    = (const float*)d_in[2];
  const float* b1    = (const float*)d_in[3];
  const float* g2    = (const float*)d_in[4];
  const float* b2    = (const float*)d_in[5];
  const float* Gq_w  = (const float*)d_in[6];
  const float* Gq_b  = (const float*)d_in[7];
  const float* Gkv_w = (const float*)d_in[8];
  const float* Gkv_b = (const float*)d_in[9];
  const float* Gp_w  = (const float*)d_in[10];
  const float* Gp_b  = (const float*)d_in[11];
  const float* Lq_w  = (const float*)d_in[12];
  const float* Lq_b  = (const float*)d_in[13];
  const float* Lkv_w = (const float*)d_in[14];
  const float* Lkv_b = (const float*)d_in[15];
  const float* Lp_w  = (const float*)d_in[16];
  const float* Lp_b  = (const float*)d_in[17];
  const float* fc1_w = (const float*)d_in[18];
  const float* fc1_b = (const float*)d_in[19];
  const float* dw_w  = (const float*)d_in[20];
  const float* dw_b  = (const float*)d_in[21];
  const float* fc2_w = (const float*)d_in[22];
  const float* fc2_b = (const float*)d_in[23];

  // ---- transposed bf16 weight arena ----
  const size_t E_GQ = 256 * 128, E_GKV = 256 * 256, E_GP = 128 * 128;
  const size_t E_LQ = 256 * 128, E_LKV = 256 * 256, E_LP = 128 * 128;
  const size_t E_F1 = 256 * 1024, E_F2 = 1024 * 256;
  char* ws = (char*)d_ws;
  bf16* Gq_t  = (bf16*)ws;
  bf16* Gkv_t = Gq_t  + E_GQ;
  bf16* Gp_t  = Gkv_t + E_GKV;
  bf16* Lq_t  = Gp_t  + E_GP;
  bf16* Lkv_t = Lq_t  + E_LQ;
  bf16* Lp_t  = Lkv_t + E_LKV;
  bf16* f1_t  = Lp_t  + E_LP;
  bf16* f2_t  = f1_t  + E_F1;
  const size_t WT_ELEMS = E_GQ + E_GKV + E_GP + E_LQ + E_LKV + E_LP + E_F1 + E_F2;
  const size_t WT_BYTES = WT_ELEMS * 2;

  // ---- activation arena ----
  const size_t SZ_ROW2 = (size_t)M_ * Cc * 2;
  const size_t SZ_HALF = (size_t)M_ * 128 * 2;
  const size_t SZ_POOL = (size_t)B_ * TG_ * Cc * 2;
  const size_t SZ_KVG  = (size_t)B_ * TG_ * 256 * 2;
  const size_t SZ_H    = (size_t)(2 * Nn) * HID_ * 2;
  char* arena = ws + WT_BYTES;
  bf16* S1 = (bf16*)(arena);
  bf16* S2 = (bf16*)(arena + SZ_ROW2);
  bf16* S3 = (bf16*)(arena + 2 * SZ_ROW2);
  bf16* S4 = (bf16*)(arena + 2 * SZ_ROW2 + SZ_HALF);
  bf16* S5 = (bf16*)(arena + 2 * SZ_ROW2 + 2 * SZ_HALF);
  bf16* poolb = (bf16*)(arena + 2 * SZ_ROW2 + 3 * SZ_HALF);
  bf16* kvG   = (bf16*)(arena + 2 * SZ_ROW2 + 3 * SZ_HALF + SZ_POOL);
  const size_t ARENA_A = 2 * SZ_ROW2 + 3 * SZ_HALF + SZ_POOL + SZ_KVG;
  bf16* xn2 = S1;
  bf16* h1  = (bf16*)(arena + SZ_ROW2);
  bf16* h2  = (bf16*)(arena + SZ_ROW2 + SZ_H);
  const size_t ARENA_B = SZ_ROW2 + 2 * SZ_H;

  float* out  = (float*)d_out;
  float* xres = (float*)d_out;
  const size_t NEED = WT_BYTES + (ARENA_A > ARENA_B ? ARENA_A : ARENA_B);
  if (ws_size < NEED) {
    guard_fill_kernel<<<16, 256, 0, stream>>>(out);
    return;
  }

  bf16* xn = S1;  bf16* xrn = S2;  bf16* qbuf = S3;  bf16* gattn = S4;  bf16* gout = S5;
  bf16* kvl = S1; bf16* lo_w = S2; bf16* qlb  = S3;  bf16* lattn = S4;

  // 0) all weights -> bf16 transposed, one kernel
  convert_all_kernel<<<2944, 256, 0, stream>>>(Gq_w, Gkv_w, Gp_w, Lq_w, Lkv_w, Lp_w,
                                               fc1_w, fc2_w, (bf16*)ws);
  // 1) LayerNorm both streams
  ln_kernel<float><<<M_, 256, 0, stream>>>(x, g1, b1, xn);
  ln_kernel<float><<<M_, 256, 0, stream>>>(xrev, g1, b1, xrn);
  // 2) 7x7 pool of xrn
  pool_kernel<<<dim3(TG_, B_), 256, 0, stream>>>(xrn, poolb);
  // 3) q = xn @ Gq_w + b
  mfma_gemm_kernel<bf16, false, false><<<dim3(1, M_ / 128), 256, 0, stream>>>(
      xn, Gq_t, Gq_b, nullptr, qbuf, M_, 128, 256);
  // 4) kv = pooled @ Gkv_w + b
  mfma_gemm_kernel<bf16, false, false><<<dim3(2, 8), 256, 0, stream>>>(
      poolb, Gkv_t, Gkv_b, nullptr, kvG, 1024, 256, 256);
  // 5) global attention (MFMA flash)
  gattn_kernel<<<dim3(Nn / 128, GH_, B_), 256, 0, stream>>>(qbuf, kvG, gattn);
  // 6) gout = gattn @ Gp_w + b
  mfma_gemm_kernel<bf16, false, false><<<dim3(1, M_ / 128), 256, 0, stream>>>(
      gattn, Gp_t, Gp_b, nullptr, gout, M_, 128, 128);
  // 7) ql = windows(xn) @ Lq_w + b
  mfma_gemm_kernel<bf16, true, false><<<dim3(1, M_ / 128), 256, 0, stream>>>(
      xn, Lq_t, Lq_b, nullptr, qlb, M_, 128, 256);
  // 8) kvl = windows(xrn) @ Lkv_w + b
  mfma_gemm_kernel<bf16, true, false><<<dim3(2, M_ / 128), 256, 0, stream>>>(
      xrn, Lkv_t, Lkv_b, nullptr, kvl, M_, 256, 256);
  // 9) local attention
  lattn_kernel<<<dim3(4, TG_, B_), 64, 0, stream>>>(qlb, kvl, lattn);
  // 10) lo = lattn @ Lp_w + b
  mfma_gemm_kernel<bf16, false, false><<<dim3(1, M_ / 128), 256, 0, stream>>>(
      lattn, Lp_t, Lp_b, nullptr, lo_w, M_, 128, 128);
  // 11) xres(=d_out) = x + concat(gout, unwin(lo)); xn2 = LN2(xres)  [fused]
  combine_ln_kernel<<<M_, 256, 0, stream>>>(x, gout, lo_w, g2, b2, xres, xn2);
  // 12-14) MLP in two halves (2 images each)
  for (int half = 0; half < 2; half++) {
    const size_t r0 = (size_t)half * 2 * Nn;
    mfma_gemm_kernel<bf16, false, false><<<dim3(8, (2 * Nn) / 128), 256, 0, stream>>>(
        xn2 + r0 * Cc, f1_t, fc1_b, nullptr, h1, 2 * Nn, 1024, 256);
    dwconv_gelu_kernel<<<dim3(4, Hh, 2), 256, 0, stream>>>(h1, dw_w, dw_b, h2);
    mfma_gemm_kernel<float, false, true><<<dim3(2, (2 * Nn) / 128), 256, 0, stream>>>(
        h2, f2_t, fc2_b, xres + r0 * Cc, out + r0 * Cc, 2 * Nn, 256, 1024);
  }
}

// Round 7
// 583.853 us; speedup vs baseline: 4.8909x; 1.1193x over previous
//
#include <hip/hip_runtime.h>
#include <hip/hip_bf16.h>
#include <math.h>

typedef __hip_bfloat16 bf16;
typedef __attribute__((ext_vector_type(8))) short bf16x8;
typedef __attribute__((ext_vector_type(4))) float f32x4;

static constexpr int B_  = 4;
static constexpr int Hh  = 112, Ww = 112;
static constexpr int Nn  = Hh * Ww;        // 12544
static constexpr int Cc  = 256;
static constexpr int M_  = B_ * Nn;        // 50176
static constexpr int GH_ = 4;
static constexpr int GD_ = 128;
static constexpr int LD_ = 128;
static constexpr int HID_ = 1024;
static constexpr int TG_ = 256;            // 16*16 windows
static constexpr int T__ = 49;             // 7*7 tokens per window
static constexpr float SCALE_ = 0.17677669529663687f;  // 32^-0.5

__device__ __forceinline__ float toF(const bf16 v)  { return __bfloat162float(v); }
__device__ __forceinline__ float toF(const float v) { return v; }
__device__ __forceinline__ void st_out(float* p, float v) { *p = v; }
__device__ __forceinline__ void st_out(bf16* p, float v)  { *p = __float2bfloat16(v); }

// windowed row r = ((b*256 + g)*49 + t)  ->  flat row b*N + n
__device__ __forceinline__ int win_row_map(int r) {
  int b  = r / Nn;
  int rr = r - b * Nn;
  int g  = rr / T__;
  int t  = rr - g * T__;
  int gh = g >> 4, gw = g & 15;
  int i  = t / 7,  j  = t - i * 7;
  int n  = (gh * 7 + i) * Ww + gw * 7 + j;
  return b * Nn + n;
}

__global__ void guard_fill_kernel(float* out) {
  out[threadIdx.x + blockIdx.x * 256] = 1.0e6f;  // sentinel: workspace guard tripped
}

// ---------------- fused weight convert+transpose for all 8 weights ----------------
__global__ __launch_bounds__(256) void convert_all_kernel(
    const float* __restrict__ s0, const float* __restrict__ s1,
    const float* __restrict__ s2, const float* __restrict__ s3,
    const float* __restrict__ s4, const float* __restrict__ s5,
    const float* __restrict__ s6, const float* __restrict__ s7,
    bf16* __restrict__ wt) {
  int idx = blockIdx.x * 256 + threadIdx.x;   // grid sized exactly: 753664 = 2944*256
  const float* W; int K, N, base;
  if      (idx < 32768)  { W = s0; K = 256;  N = 128;  base = 0; }
  else if (idx < 98304)  { W = s1; K = 256;  N = 256;  base = 32768; }
  else if (idx < 114688) { W = s2; K = 128;  N = 128;  base = 98304; }
  else if (idx < 147456) { W = s3; K = 256;  N = 128;  base = 114688; }
  else if (idx < 212992) { W = s4; K = 256;  N = 256;  base = 147456; }
  else if (idx < 229376) { W = s5; K = 128;  N = 128;  base = 212992; }
  else if (idx < 491520) { W = s6; K = 256;  N = 1024; base = 229376; }
  else                   { W = s7; K = 1024; N = 256;  base = 491520; }
  int loc = idx - base;
  int n = loc / K, k = loc - n * K;
  wt[idx] = __float2bfloat16(W[(size_t)k * N + n]);
}

// ---------------- dual LayerNorm: wave per row, float4/lane, shuffle-only reduce ----------------
__global__ __launch_bounds__(256) void ln_dual_kernel(const float* __restrict__ x,
                                                      const float* __restrict__ xr,
                                                      const float* __restrict__ g,
                                                      const float* __restrict__ bta,
                                                      bf16* __restrict__ xn,
                                                      bf16* __restrict__ xrn) {
  const int tid = threadIdx.x;
  const int row = blockIdx.x * 4 + (tid >> 6);
  const int lane = tid & 63;
  const int c0 = lane * 4;
  const float* src = blockIdx.y ? xr : x;
  bf16* dst = blockIdx.y ? xrn : xn;
  float4 v = *(const float4*)(src + (size_t)row * Cc + c0);
  float s  = v.x + v.y + v.z + v.w;
  float ss = v.x * v.x + v.y * v.y + v.z * v.z + v.w * v.w;
  #pragma unroll
  for (int off = 1; off < 64; off <<= 1) {
    s  += __shfl_xor(s, off);
    ss += __shfl_xor(ss, off);
  }
  float mean = s * (1.0f / Cc);
  float var  = ss * (1.0f / Cc) - mean * mean;
  float r = rsqrtf(var + 1e-5f);
  float4 gv = *(const float4*)(g + c0);
  float4 bv = *(const float4*)(bta + c0);
  bf16 o[4];
  o[0] = __float2bfloat16((v.x - mean) * r * gv.x + bv.x);
  o[1] = __float2bfloat16((v.y - mean) * r * gv.y + bv.y);
  o[2] = __float2bfloat16((v.z - mean) * r * gv.z + bv.z);
  o[3] = __float2bfloat16((v.w - mean) * r * gv.w + bv.w);
  *(uint2*)(dst + (size_t)row * Cc + c0) = *(uint2*)o;
}

// ---------------- 7x7 average pool: 64 threads, 4 channels/lane ----------------
__global__ __launch_bounds__(64) void pool_kernel(const bf16* __restrict__ xrn,
                                                  bf16* __restrict__ pooled) {
  const int lane = threadIdx.x;
  const int c0 = lane * 4;
  const int g  = blockIdx.x;   // gh*16+gw
  const int b  = blockIdx.y;
  const int gh = g >> 4, gw = g & 15;
  float acc[4] = {};
  union U4 { uint2 u; bf16 e[4]; };
  #pragma unroll
  for (int i = 0; i < 7; i++)
    for (int j = 0; j < 7; j++) {
      int n = (gh * 7 + i) * Ww + gw * 7 + j;
      U4 r4;
      r4.u = *(const uint2*)(xrn + ((size_t)b * Nn + n) * Cc + c0);
      #pragma unroll
      for (int u = 0; u < 4; u++) acc[u] += toF(r4.e[u]);
    }
  bf16 o[4];
  #pragma unroll
  for (int u = 0; u < 4; u++) o[u] = __float2bfloat16(acc[u] * (1.0f / 49.0f));
  *(uint2*)(pooled + ((size_t)b * TG_ + g) * Cc + c0) = *(uint2*)o;
}

// ---------------- MFMA GEMM: out[M,N] = A[M,K](bf16) @ Wt[N,K](bf16,transposed) + bias ----------------
template <typename OutT, bool WIN_A, bool RES>
__global__ __launch_bounds__(256) void mfma_gemm_kernel(const bf16* __restrict__ A,
                                                        const bf16* __restrict__ Wt,
                                                        const float* __restrict__ bias,
                                                        const float* __restrict__ res,
                                                        OutT* __restrict__ out,
                                                        int M, int N, int K) {
  __shared__ __align__(16) bf16 As[128][40];
  __shared__ __align__(16) bf16 Bs[128][40];
  const int tid = threadIdx.x;
  const int bm = blockIdx.y * 128, bn = blockIdx.x * 128;
  const int lane = tid & 63, w = tid >> 6;
  const int wm = (w >> 1) * 64, wn = (w & 1) * 64;
  const int sr = tid >> 1;
  const int sc = (tid & 1) * 16;
  const int arow = bm + sr;
  const int asrc = WIN_A ? win_row_map(arow) : arow;
  const bf16* Ag = A  + (size_t)asrc * K + sc;
  const bf16* Bg = Wt + (size_t)(bn + sr) * K + sc;

  f32x4 acc[4][4];
  #pragma unroll
  for (int i = 0; i < 4; i++)
    #pragma unroll
    for (int j = 0; j < 4; j++) acc[i][j] = (f32x4){0.f, 0.f, 0.f, 0.f};

  const int mrow = wm + (lane & 15);
  const int nrow = wn + (lane & 15);
  const int koct = (lane >> 4) * 8;

  for (int k0 = 0; k0 < K; k0 += 32) {
    uint4 a0 = *(const uint4*)(Ag + k0);
    uint4 a1 = *(const uint4*)(Ag + k0 + 8);
    uint4 b0 = *(const uint4*)(Bg + k0);
    uint4 b1 = *(const uint4*)(Bg + k0 + 8);
    *(uint4*)&As[sr][sc]     = a0;
    *(uint4*)&As[sr][sc + 8] = a1;
    *(uint4*)&Bs[sr][sc]     = b0;
    *(uint4*)&Bs[sr][sc + 8] = b1;
    __syncthreads();
    bf16x8 af[4], bfr[4];
    #pragma unroll
    for (int i = 0; i < 4; i++) af[i]  = *(const bf16x8*)&As[mrow + i * 16][koct];
    #pragma unroll
    for (int j = 0; j < 4; j++) bfr[j] = *(const bf16x8*)&Bs[nrow + j * 16][koct];
    #pragma unroll
    for (int i = 0; i < 4; i++)
      #pragma unroll
      for (int j = 0; j < 4; j++)
        acc[i][j] = __builtin_amdgcn_mfma_f32_16x16x32_bf16(af[i], bfr[j], acc[i][j], 0, 0, 0);
    __syncthreads();
  }

  const int r0  = (lane >> 4) * 4;
  const int cl  = lane & 15;
  #pragma unroll
  for (int j = 0; j < 4; j++) {
    const int col = bn + wn + j * 16 + cl;
    const float bv = bias[col];
    #pragma unroll
    for (int i = 0; i < 4; i++) {
      const int rowb = bm + wm + i * 16 + r0;
      #pragma unroll
      for (int r = 0; r < 4; r++) {
        size_t ro = (size_t)(rowb + r) * N + col;
        float v = acc[i][j][r] + bv;
        if (RES) v += res[ro];
        st_out(out + ro, v);
      }
    }
  }
}

// ---------------- MFMA flash global attention ----------------
__global__ __launch_bounds__(256) void gattn_kernel(const bf16* __restrict__ q,
                                                    const bf16* __restrict__ kv,
                                                    bf16* __restrict__ out) {
  __shared__ __align__(16) bf16 Ks[256][40];
  __shared__ __align__(16) bf16 Vt[32][264];
  __shared__ __align__(16) bf16 Ps[4][32][40];
  const int tid = threadIdx.x;
  const int lane = tid & 63, w = tid >> 6;
  const int h = blockIdx.y, b = blockIdx.z;
  const int n0 = blockIdx.x * 128;
  const int r16 = lane & 15, oct = (lane >> 4) * 8;
  const bf16* kvb = kv + (size_t)b * TG_ * 256;

  {
    const int key = tid;
    const bf16* kp = kvb + (size_t)key * 256 + h * 32;
    *(uint4*)&Ks[key][0]  = *(const uint4*)(kp);
    *(uint4*)&Ks[key][8]  = *(const uint4*)(kp + 8);
    *(uint4*)&Ks[key][16] = *(const uint4*)(kp + 16);
    *(uint4*)&Ks[key][24] = *(const uint4*)(kp + 24);
    union { uint4 u[4]; bf16 e[32]; } vv;
    vv.u[0] = *(const uint4*)(kp + 128);
    vv.u[1] = *(const uint4*)(kp + 136);
    vv.u[2] = *(const uint4*)(kp + 144);
    vv.u[3] = *(const uint4*)(kp + 152);
    #pragma unroll
    for (int d = 0; d < 32; d++) Vt[d][key] = vv.e[d];
  }
  const size_t qbase0 = ((size_t)(b * Nn + n0 + w * 32 + r16)) * GD_ + h * 32 + oct;
  bf16x8 aq0 = *(const bf16x8*)(q + qbase0);
  bf16x8 aq1 = *(const bf16x8*)(q + qbase0 + (size_t)16 * GD_);
  __syncthreads();

  f32x4 rs0 = {0.f, 0.f, 0.f, 0.f}, rs1 = {0.f, 0.f, 0.f, 0.f};
  f32x4 ov[2][2];
  #pragma unroll
  for (int i = 0; i < 2; i++)
    #pragma unroll
    for (int dt = 0; dt < 2; dt++) ov[i][dt] = (f32x4){0.f, 0.f, 0.f, 0.f};

  for (int c0 = 0; c0 < 256; c0 += 32) {
    #pragma unroll
    for (int t = 0; t < 2; t++) {
      bf16x8 bk = *(const bf16x8*)&Ks[c0 + t * 16 + r16][oct];
      f32x4 s0 = __builtin_amdgcn_mfma_f32_16x16x32_bf16(aq0, bk, (f32x4){0.f,0.f,0.f,0.f}, 0, 0, 0);
      f32x4 s1 = __builtin_amdgcn_mfma_f32_16x16x32_bf16(aq1, bk, (f32x4){0.f,0.f,0.f,0.f}, 0, 0, 0);
      const int prow = (lane >> 4) * 4;
      const int pcol = t * 16 + r16;
      #pragma unroll
      for (int r = 0; r < 4; r++) {
        bf16 pb0 = __float2bfloat16(__expf(s0[r] * SCALE_));
        bf16 pb1 = __float2bfloat16(__expf(s1[r] * SCALE_));
        rs0[r] += toF(pb0);
        rs1[r] += toF(pb1);
        Ps[w][prow + r][pcol]      = pb0;
        Ps[w][16 + prow + r][pcol] = pb1;
      }
    }
    bf16x8 ap0 = *(const bf16x8*)&Ps[w][r16][oct];
    bf16x8 ap1 = *(const bf16x8*)&Ps[w][16 + r16][oct];
    #pragma unroll
    for (int dt = 0; dt < 2; dt++) {
      bf16x8 bv = *(const bf16x8*)&Vt[dt * 16 + r16][c0 + oct];
      ov[0][dt] = __builtin_amdgcn_mfma_f32_16x16x32_bf16(ap0, bv, ov[0][dt], 0, 0, 0);
      ov[1][dt] = __builtin_amdgcn_mfma_f32_16x16x32_bf16(ap1, bv, ov[1][dt], 0, 0, 0);
    }
  }
  #pragma unroll
  for (int off = 1; off < 16; off <<= 1) {
    #pragma unroll
    for (int r = 0; r < 4; r++) {
      rs0[r] += __shfl_xor(rs0[r], off);
      rs1[r] += __shfl_xor(rs1[r], off);
    }
  }
  const int orow0 = b * Nn + n0 + w * 32 + (lane >> 4) * 4;
  #pragma unroll
  for (int r = 0; r < 4; r++) {
    float inv0 = 1.0f / rs0[r];
    float inv1 = 1.0f / rs1[r];
    size_t ro0 = (size_t)(orow0 + r) * GD_ + h * 32;
    size_t ro1 = ro0 + (size_t)16 * GD_;
    #pragma unroll
    for (int dt = 0; dt < 2; dt++) {
      out[ro0 + dt * 16 + r16] = __float2bfloat16(ov[0][dt][r] * inv0);
      out[ro1 + dt * 16 + r16] = __float2bfloat16(ov[1][dt][r] * inv1);
    }
  }
}

// ---------------- local window attention: one wave per (b, window, head) ----------------
__global__ __launch_bounds__(64) void lattn_kernel(const bf16* __restrict__ ql,
                                                   const bf16* __restrict__ kvl,
                                                   bf16* __restrict__ out) {
  __shared__ float ks[T__ * 32];
  __shared__ float vs[T__ * 32];
  const int tid = threadIdx.x;
  const int h = blockIdx.x, g = blockIdx.y, b = blockIdx.z;
  const size_t base = (((size_t)b * TG_ + g) * T__) * 256;
  for (int idx = tid; idx < T__ * 32; idx += 64) {
    int m = idx >> 5, d = idx & 31;
    ks[idx] = toF(kvl[base + (size_t)m * 256 + h * 32 + d]);
    vs[idx] = toF(kvl[base + (size_t)m * 256 + 128 + h * 32 + d]);
  }
  __syncthreads();
  if (tid < T__) {
    const size_t qoff = (((size_t)b * TG_ + g) * T__ + tid) * LD_ + h * 32;
    float qv[32];
    #pragma unroll
    for (int d = 0; d < 32; d++) qv[d] = toF(ql[qoff + d]) * SCALE_;
    float l = 0.f;
    float acc[32] = {};
    for (int m = 0; m < T__; m++) {
      const float* kr = ks + m * 32;
      const float* vr = vs + m * 32;
      float s = 0.f;
      #pragma unroll
      for (int d = 0; d < 32; d++) s = fmaf(qv[d], kr[d], s);
      float p = __expf(fminf(s, 60.f));
      l += p;
      #pragma unroll
      for (int d = 0; d < 32; d++) acc[d] = fmaf(p, vr[d], acc[d]);
    }
    const float rl = 1.0f / l;
    #pragma unroll
    for (int d = 0; d < 32; d++) out[qoff + d] = __float2bfloat16(acc[d] * rl);
  }
}

// ---------------- combine + LN2 fused: wave per row, float4/lane ----------------
__global__ __launch_bounds__(256) void combine_ln_kernel(const float* __restrict__ x,
                                                         const bf16* __restrict__ gout,
                                                         const bf16* __restrict__ lo_w,
                                                         const float* __restrict__ g2,
                                                         const float* __restrict__ b2,
                                                         float* __restrict__ xres,
                                                         bf16* __restrict__ xn2) {
  const int tid = threadIdx.x;
  const int row = blockIdx.x * 4 + (tid >> 6);
  const int lane = tid & 63;
  const int c0 = lane * 4;
  // windowed row (wave-uniform)
  int b = row / Nn, n = row - b * Nn;
  int y = n / Ww, xx = n - y * Ww;
  int gh = y / 7, i = y - gh * 7;
  int gw = xx / 7, j = xx - gw * 7;
  size_t wrow = ((size_t)b * TG_ + gh * 16 + gw) * T__ + i * 7 + j;
  union U4 { uint2 u; bf16 e[4]; } r4;
  if (lane < 32) r4.u = *(const uint2*)(gout + (size_t)row * GD_ + c0);
  else           r4.u = *(const uint2*)(lo_w + wrow * LD_ + (c0 - 128));
  float4 v = *(const float4*)(x + (size_t)row * Cc + c0);
  v.x += toF(r4.e[0]); v.y += toF(r4.e[1]); v.z += toF(r4.e[2]); v.w += toF(r4.e[3]);
  *(float4*)(xres + (size_t)row * Cc + c0) = v;
  float s  = v.x + v.y + v.z + v.w;
  float ss = v.x * v.x + v.y * v.y + v.z * v.z + v.w * v.w;
  #pragma unroll
  for (int off = 1; off < 64; off <<= 1) {
    s  += __shfl_xor(s, off);
    ss += __shfl_xor(ss, off);
  }
  float mean = s * (1.0f / Cc);
  float var  = ss * (1.0f / Cc) - mean * mean;
  float r = rsqrtf(var + 1e-5f);
  float4 gv = *(const float4*)(g2 + c0);
  float4 bv = *(const float4*)(b2 + c0);
  bf16 o[4];
  o[0] = __float2bfloat16((v.x - mean) * r * gv.x + bv.x);
  o[1] = __float2bfloat16((v.y - mean) * r * gv.y + bv.y);
  o[2] = __float2bfloat16((v.z - mean) * r * gv.z + bv.z);
  o[3] = __float2bfloat16((v.w - mean) * r * gv.w + bv.w);
  *(uint2*)(xn2 + (size_t)row * Cc + c0) = *(uint2*)o;
}

// ---------------- depthwise 3x3 conv + bias + exact GELU: sliding-window row walker ----------------
__global__ __launch_bounds__(256) void dwconv_gelu_kernel(const bf16* __restrict__ h1,
                                                          const float* __restrict__ w,
                                                          const float* __restrict__ bias,
                                                          bf16* __restrict__ h2) {
  const int tid = threadIdx.x;
  const int c0 = tid * 4;
  const int img = blockIdx.z, y = blockIdx.y;
  const int xt = blockIdx.x * 28;
  const size_t ibase = (size_t)img * Nn * HID_;

  float wreg[9][4], breg[4];
  #pragma unroll
  for (int u = 0; u < 4; u++) {
    breg[u] = bias[c0 + u];
    #pragma unroll
    for (int t = 0; t < 9; t++) wreg[t][u] = w[(c0 + u) * 9 + t];
  }

  const bf16* rowp[3];
  bool rok[3];
  #pragma unroll
  for (int r = 0; r < 3; r++) {
    int yy = y - 1 + r;
    rok[r] = (yy >= 0 && yy < Hh);
    rowp[r] = h1 + ibase + (size_t)(rok[r] ? yy : 0) * Ww * HID_ + c0;
  }

  float wa[3][4], wb[3][4], wc[3][4];
  union U4 { ushort2 u2[2]; bf16 e[4]; };
  auto loadcol = [&](int xcol, float v[3][4]) {
    if (xcol < 0 || xcol >= Ww) {
      #pragma unroll
      for (int r = 0; r < 3; r++)
        #pragma unroll
        for (int u = 0; u < 4; u++) v[r][u] = 0.f;
      return;
    }
    #pragma unroll
    for (int r = 0; r < 3; r++) {
      if (rok[r]) {
        U4 raw;
        *(uint2*)&raw = *(const uint2*)(rowp[r] + (size_t)xcol * HID_);
        #pragma unroll
        for (int u = 0; u < 4; u++) v[r][u] = toF(raw.e[u]);
      } else {
        #pragma unroll
        for (int u = 0; u < 4; u++) v[r][u] = 0.f;
      }
    }
  };
  loadcol(xt - 1, wa);
  loadcol(xt, wb);

  for (int xx = 0; xx < 28; xx++) {
    const int x = xt + xx;
    loadcol(x + 1, wc);
    bf16 res[4];
    #pragma unroll
    for (int u = 0; u < 4; u++) {
      float a = breg[u];
      a = fmaf(wa[0][u], wreg[0][u], a);
      a = fmaf(wb[0][u], wreg[1][u], a);
      a = fmaf(wc[0][u], wreg[2][u], a);
      a = fmaf(wa[1][u], wreg[3][u], a);
      a = fmaf(wb[1][u], wreg[4][u], a);
      a = fmaf(wc[1][u], wreg[5][u], a);
      a = fmaf(wa[2][u], wreg[6][u], a);
      a = fmaf(wb[2][u], wreg[7][u], a);
      a = fmaf(wc[2][u], wreg[8][u], a);
      float gl = 0.5f * a * (1.0f + erff(a * 0.7071067811865475f));
      res[u] = __float2bfloat16(gl);
    }
    *(uint2*)(h2 + ibase + (size_t)(y * Ww + x) * HID_ + c0) = *(uint2*)res;
    #pragma unroll
    for (int r = 0; r < 3; r++)
      #pragma unroll
      for (int u = 0; u < 4; u++) { wa[r][u] = wb[r][u]; wb[r][u] = wc[r][u]; }
  }
}

extern "C" void kernel_launch(void* const* d_in, const int* in_sizes, int n_in,
                              void* d_out, int out_size, void* d_ws, size_t ws_size,
                              hipStream_t stream) {
  const float* x     = (const float*)d_in[0];
  const float* xrev  = (const float*)d_in[1];
  const float* g1    = (const float*)d_in[2];
  const float* b1    = (const float*)d_in[3];
  const float* g2    = (const float*)d_in[4];
  const float* b2    = (const float*)d_in[5];
  const float* Gq_w  = (const float*)d_in[6];
  const float* Gq_b  = (const float*)d_in[7];
  const float* Gkv_w = (const float*)d_in[8];
  const float* Gkv_b = (const float*)d_in[9];
  const float* Gp_w  = (const float*)d_in[10];
  const float* Gp_b  = (const float*)d_in[11];
  const float* Lq_w  = (const float*)d_in[12];
  const float* Lq_b  = (const float*)d_in[13];
  const float* Lkv_w = (const float*)d_in[14];
  const float* Lkv_b = (const float*)d_in[15];
  const float* Lp_w  = (const float*)d_in[16];
  const float* Lp_b  = (const float*)d_in[17];
  const float* fc1_w = (const float*)d_in[18];
  const float* fc1_b = (const float*)d_in[19];
  const float* dw_w  = (const float*)d_in[20];
  const float* dw_b  = (const float*)d_in[21];
  const float* fc2_w = (const float*)d_in[22];
  const float* fc2_b = (const float*)d_in[23];

  // ---- transposed bf16 weight arena ----
  const size_t E_GQ = 256 * 128, E_GKV = 256 * 256, E_GP = 128 * 128;
  const size_t E_LQ = 256 * 128, E_LKV = 256 * 256, E_LP = 128 * 128;
  const size_t E_F1 = 256 * 1024, E_F2 = 1024 * 256;
  char* ws = (char*)d_ws;
  bf16* Gq_t  = (bf16*)ws;
  bf16* Gkv_t = Gq_t  + E_GQ;
  bf16* Gp_t  = Gkv_t + E_GKV;
  bf16* Lq_t  = Gp_t  + E_GP;
  bf16* Lkv_t = Lq_t  + E_LQ;
  bf16* Lp_t  = Lkv_t + E_LKV;
  bf16* f1_t  = Lp_t  + E_LP;
  bf16* f2_t  = f1_t  + E_F1;
  const size_t WT_ELEMS = E_GQ + E_GKV + E_GP + E_LQ + E_LKV + E_LP + E_F1 + E_F2;
  const size_t WT_BYTES = WT_ELEMS * 2;

  // ---- activation arena ----
  const size_t SZ_ROW2 = (size_t)M_ * Cc * 2;
  const size_t SZ_HALF = (size_t)M_ * 128 * 2;
  const size_t SZ_POOL = (size_t)B_ * TG_ * Cc * 2;
  const size_t SZ_KVG  = (size_t)B_ * TG_ * 256 * 2;
  const size_t SZ_H    = (size_t)(2 * Nn) * HID_ * 2;
  char* arena = ws + WT_BYTES;
  bf16* S1 = (bf16*)(arena);
  bf16* S2 = (bf16*)(arena + SZ_ROW2);
  bf16* S3 = (bf16*)(arena + 2 * SZ_ROW2);
  bf16* S4 = (bf16*)(arena + 2 * SZ_ROW2 + SZ_HALF);
  bf16* S5 = (bf16*)(arena + 2 * SZ_ROW2 + 2 * SZ_HALF);
  bf16* poolb = (bf16*)(arena + 2 * SZ_ROW2 + 3 * SZ_HALF);
  bf16* kvG   = (bf16*)(arena + 2 * SZ_ROW2 + 3 * SZ_HALF + SZ_POOL);
  const size_t ARENA_A = 2 * SZ_ROW2 + 3 * SZ_HALF + SZ_POOL + SZ_KVG;
  bf16* xn2 = S1;
  bf16* h1  = (bf16*)(arena + SZ_ROW2);
  bf16* h2  = (bf16*)(arena + SZ_ROW2 + SZ_H);
  const size_t ARENA_B = SZ_ROW2 + 2 * SZ_H;

  float* out  = (float*)d_out;
  float* xres = (float*)d_out;
  const size_t NEED = WT_BYTES + (ARENA_A > ARENA_B ? ARENA_A : ARENA_B);
  if (ws_size < NEED) {
    guard_fill_kernel<<<16, 256, 0, stream>>>(out);
    return;
  }

  bf16* xn = S1;  bf16* xrn = S2;  bf16* qbuf = S3;  bf16* gattn = S4;  bf16* gout = S5;
  bf16* kvl = S1; bf16* lo_w = S2; bf16* qlb  = S3;  bf16* lattn = S4;

  // 0) all weights -> bf16 transposed, one kernel
  convert_all_kernel<<<2944, 256, 0, stream>>>(Gq_w, Gkv_w, Gp_w, Lq_w, Lkv_w, Lp_w,
                                               fc1_w, fc2_w, (bf16*)ws);
  // 1) LayerNorm both streams, one launch (wave-per-row)
  ln_dual_kernel<<<dim3(M_ / 4, 2), 256, 0, stream>>>(x, xrev, g1, b1, xn, xrn);
  // 2) 7x7 pool of xrn
  pool_kernel<<<dim3(TG_, B_), 64, 0, stream>>>(xrn, poolb);
  // 3) q = xn @ Gq_w + b
  mfma_gemm_kernel<bf16, false, false><<<dim3(1, M_ / 128), 256, 0, stream>>>(
      xn, Gq_t, Gq_b, nullptr, qbuf, M_, 128, 256);
  // 4) kv = pooled @ Gkv_w + b
  mfma_gemm_kernel<bf16, false, false><<<dim3(2, 8), 256, 0, stream>>>(
      poolb, Gkv_t, Gkv_b, nullptr, kvG, 1024, 256, 256);
  // 5) global attention (MFMA flash)
  gattn_kernel<<<dim3(Nn / 128, GH_, B_), 256, 0, stream>>>(qbuf, kvG, gattn);
  // 6) gout = gattn @ Gp_w + b
  mfma_gemm_kernel<bf16, false, false><<<dim3(1, M_ / 128), 256, 0, stream>>>(
      gattn, Gp_t, Gp_b, nullptr, gout, M_, 128, 128);
  // 7) ql = windows(xn) @ Lq_w + b
  mfma_gemm_kernel<bf16, true, false><<<dim3(1, M_ / 128), 256, 0, stream>>>(
      xn, Lq_t, Lq_b, nullptr, qlb, M_, 128, 256);
  // 8) kvl = windows(xrn) @ Lkv_w + b
  mfma_gemm_kernel<bf16, true, false><<<dim3(2, M_ / 128), 256, 0, stream>>>(
      xrn, Lkv_t, Lkv_b, nullptr, kvl, M_, 256, 256);
  // 9) local attention
  lattn_kernel<<<dim3(4, TG_, B_), 64, 0, stream>>>(qlb, kvl, lattn);
  // 10) lo = lattn @ Lp_w + b
  mfma_gemm_kernel<bf16, false, false><<<dim3(1, M_ / 128), 256, 0, stream>>>(
      lattn, Lp_t, Lp_b, nullptr, lo_w, M_, 128, 128);
  // 11) xres(=d_out) = x + concat(gout, unwin(lo)); xn2 = LN2(xres)  [fused, wave-per-row]
  combine_ln_kernel<<<M_ / 4, 256, 0, stream>>>(x, gout, lo_w, g2, b2, xres, xn2);
  // 12-14) MLP in two halves (2 images each)
  for (int half = 0; half < 2; half++) {
    const size_t r0 = (size_t)half * 2 * Nn;
    mfma_gemm_kernel<bf16, false, false><<<dim3(8, (2 * Nn) / 128), 256, 0, stream>>>(
        xn2 + r0 * Cc, f1_t, fc1_b, nullptr, h1, 2 * Nn, 1024, 256);
    dwconv_gelu_kernel<<<dim3(4, Hh, 2), 256, 0, stream>>>(h1, dw_w, dw_b, h2);
    mfma_gemm_kernel<float, false, true><<<dim3(2, (2 * Nn) / 128), 256, 0, stream>>>(
        h2, f2_t, fc2_b, xres + r0 * Cc, out + r0 * Cc, 2 * Nn, 256, 1024);
  }
}

// Round 8
// 561.778 us; speedup vs baseline: 5.0831x; 1.0393x over previous
//
#include <hip/hip_runtime.h>
#include <hip/hip_bf16.h>
#include <math.h>

typedef __hip_bfloat16 bf16;
typedef __attribute__((ext_vector_type(8))) short bf16x8;
typedef __attribute__((ext_vector_type(4))) float f32x4;

static constexpr int B_  = 4;
static constexpr int Hh  = 112, Ww = 112;
static constexpr int Nn  = Hh * Ww;        // 12544
static constexpr int Cc  = 256;
static constexpr int M_  = B_ * Nn;        // 50176
static constexpr int GH_ = 4;
static constexpr int GD_ = 128;
static constexpr int LD_ = 128;
static constexpr int HID_ = 1024;
static constexpr int TG_ = 256;            // 16*16 windows
static constexpr int T__ = 49;             // 7*7 tokens per window
static constexpr float SCALE_ = 0.17677669529663687f;  // 32^-0.5

__device__ __forceinline__ float toF(const bf16 v)  { return __bfloat162float(v); }
__device__ __forceinline__ float toF(const float v) { return v; }
__device__ __forceinline__ void st_out(float* p, float v) { *p = v; }
__device__ __forceinline__ void st_out(bf16* p, float v)  { *p = __float2bfloat16(v); }

// async global->LDS 16B copy (direct-to-LDS, no VGPR roundtrip). LDS dest is
// wave-uniform base + lane*16 — caller must arrange lane-ordered contiguity.
__device__ __forceinline__ void gload_lds16(const bf16* g, bf16* l) {
  using gvoid = const __attribute__((address_space(1))) void;
  using lvoid = __attribute__((address_space(3))) void;
  __builtin_amdgcn_global_load_lds((gvoid*)g, (lvoid*)l, 16, 0, 0);
}

// windowed row r = ((b*256 + g)*49 + t)  ->  flat row b*N + n
__device__ __forceinline__ int win_row_map(int r) {
  int b  = r / Nn;
  int rr = r - b * Nn;
  int g  = rr / T__;
  int t  = rr - g * T__;
  int gh = g >> 4, gw = g & 15;
  int i  = t / 7,  j  = t - i * 7;
  int n  = (gh * 7 + i) * Ww + gw * 7 + j;
  return b * Nn + n;
}

__global__ void guard_fill_kernel(float* out) {
  out[threadIdx.x + blockIdx.x * 256] = 1.0e6f;  // sentinel: workspace guard tripped
}

// ---------------- fused weight convert+transpose for all 8 weights ----------------
__global__ __launch_bounds__(256) void convert_all_kernel(
    const float* __restrict__ s0, const float* __restrict__ s1,
    const float* __restrict__ s2, const float* __restrict__ s3,
    const float* __restrict__ s4, const float* __restrict__ s5,
    const float* __restrict__ s6, const float* __restrict__ s7,
    bf16* __restrict__ wt) {
  int idx = blockIdx.x * 256 + threadIdx.x;   // grid sized exactly: 753664 = 2944*256
  const float* W; int K, N, base;
  if      (idx < 32768)  { W = s0; K = 256;  N = 128;  base = 0; }
  else if (idx < 98304)  { W = s1; K = 256;  N = 256;  base = 32768; }
  else if (idx < 114688) { W = s2; K = 128;  N = 128;  base = 98304; }
  else if (idx < 147456) { W = s3; K = 256;  N = 128;  base = 114688; }
  else if (idx < 212992) { W = s4; K = 256;  N = 256;  base = 147456; }
  else if (idx < 229376) { W = s5; K = 128;  N = 128;  base = 212992; }
  else if (idx < 491520) { W = s6; K = 256;  N = 1024; base = 229376; }
  else                   { W = s7; K = 1024; N = 256;  base = 491520; }
  int loc = idx - base;
  int n = loc / K, k = loc - n * K;
  wt[idx] = __float2bfloat16(W[(size_t)k * N + n]);
}

// ---------------- dual LayerNorm: wave per row, float4/lane, shuffle-only reduce ----------------
__global__ __launch_bounds__(256) void ln_dual_kernel(const float* __restrict__ x,
                                                      const float* __restrict__ xr,
                                                      const float* __restrict__ g,
                                                      const float* __restrict__ bta,
                                                      bf16* __restrict__ xn,
                                                      bf16* __restrict__ xrn) {
  const int tid = threadIdx.x;
  const int row = blockIdx.x * 4 + (tid >> 6);
  const int lane = tid & 63;
  const int c0 = lane * 4;
  const float* src = blockIdx.y ? xr : x;
  bf16* dst = blockIdx.y ? xrn : xn;
  float4 v = *(const float4*)(src + (size_t)row * Cc + c0);
  float s  = v.x + v.y + v.z + v.w;
  float ss = v.x * v.x + v.y * v.y + v.z * v.z + v.w * v.w;
  #pragma unroll
  for (int off = 1; off < 64; off <<= 1) {
    s  += __shfl_xor(s, off);
    ss += __shfl_xor(ss, off);
  }
  float mean = s * (1.0f / Cc);
  float var  = ss * (1.0f / Cc) - mean * mean;
  float r = rsqrtf(var + 1e-5f);
  float4 gv = *(const float4*)(g + c0);
  float4 bv = *(const float4*)(bta + c0);
  bf16 o[4];
  o[0] = __float2bfloat16((v.x - mean) * r * gv.x + bv.x);
  o[1] = __float2bfloat16((v.y - mean) * r * gv.y + bv.y);
  o[2] = __float2bfloat16((v.z - mean) * r * gv.z + bv.z);
  o[3] = __float2bfloat16((v.w - mean) * r * gv.w + bv.w);
  *(uint2*)(dst + (size_t)row * Cc + c0) = *(uint2*)o;
}

// ---------------- 7x7 average pool: 64 threads, 4 channels/lane ----------------
__global__ __launch_bounds__(64) void pool_kernel(const bf16* __restrict__ xrn,
                                                  bf16* __restrict__ pooled) {
  const int lane = threadIdx.x;
  const int c0 = lane * 4;
  const int g  = blockIdx.x;   // gh*16+gw
  const int b  = blockIdx.y;
  const int gh = g >> 4, gw = g & 15;
  float acc[4] = {};
  union U4 { uint2 u; bf16 e[4]; };
  #pragma unroll
  for (int i = 0; i < 7; i++)
    for (int j = 0; j < 7; j++) {
      int n = (gh * 7 + i) * Ww + gw * 7 + j;
      U4 r4;
      r4.u = *(const uint2*)(xrn + ((size_t)b * Nn + n) * Cc + c0);
      #pragma unroll
      for (int u = 0; u < 4; u++) acc[u] += toF(r4.e[u]);
    }
  bf16 o[4];
  #pragma unroll
  for (int u = 0; u < 4; u++) o[u] = __float2bfloat16(acc[u] * (1.0f / 49.0f));
  *(uint2*)(pooled + ((size_t)b * TG_ + g) * Cc + c0) = *(uint2*)o;
}

// ---------------- MFMA GEMM with direct global->LDS staging (m97 recipe) ----------------
// out[M,N] = A[M,K](bf16) @ Wt[N,K](bf16,transposed) + bias; M%128==0, N%128==0, K%32==0.
template <typename OutT, bool WIN_A, bool RES>
__global__ __launch_bounds__(256) void mfma_gemm_kernel(const bf16* __restrict__ A,
                                                        const bf16* __restrict__ Wt,
                                                        const float* __restrict__ bias,
                                                        const float* __restrict__ res,
                                                        OutT* __restrict__ out,
                                                        int M, int N, int K) {
  // unpadded: global_load_lds lands at base + lane*16 (lane-ordered rows of 32 bf16)
  __shared__ __align__(16) bf16 As[128 * 32];
  __shared__ __align__(16) bf16 Bs[128 * 32];
  const int tid = threadIdx.x;
  const int bm = blockIdx.y * 128, bn = blockIdx.x * 128;
  const int lane = tid & 63, w = tid >> 6;
  const int wm = (w >> 1) * 64, wn = (w & 1) * 64;

  // staging map: wave w covers rows [w*32, w*32+32); instr i covers 16 rows.
  // lane l -> row w*32 + i*16 + (l>>2), k-chunk (l&3)*8  (LDS offset = base + l*16)
  const int srow0 = w * 32 + (lane >> 2);
  const int srow1 = srow0 + 16;
  const int kq    = (lane & 3) * 8;
  const int ar0 = bm + srow0, ar1 = bm + srow1;
  const int as0 = WIN_A ? win_row_map(ar0) : ar0;
  const int as1 = WIN_A ? win_row_map(ar1) : ar1;
  const bf16* Ag0 = A  + (size_t)as0 * K + kq;
  const bf16* Ag1 = A  + (size_t)as1 * K + kq;
  const bf16* Bg0 = Wt + (size_t)(bn + srow0) * K + kq;
  const bf16* Bg1 = Wt + (size_t)(bn + srow1) * K + kq;
  bf16* Al0 = &As[srow0 * 32 + kq];
  bf16* Al1 = &As[srow1 * 32 + kq];
  bf16* Bl0 = &Bs[srow0 * 32 + kq];
  bf16* Bl1 = &Bs[srow1 * 32 + kq];

  f32x4 acc[4][4];
  #pragma unroll
  for (int i = 0; i < 4; i++)
    #pragma unroll
    for (int j = 0; j < 4; j++) acc[i][j] = (f32x4){0.f, 0.f, 0.f, 0.f};

  const int r16  = lane & 15;
  const int koct = (lane >> 4) * 8;
  const int mrow = wm + r16;
  const int nrow = wn + r16;

  for (int k0 = 0; k0 < K; k0 += 32) {
    gload_lds16(Ag0 + k0, Al0);
    gload_lds16(Ag1 + k0, Al1);
    gload_lds16(Bg0 + k0, Bl0);
    gload_lds16(Bg1 + k0, Bl1);
    __syncthreads();   // drains vmcnt (global_load_lds) before any frag read
    bf16x8 af[4], bfr[4];
    #pragma unroll
    for (int i = 0; i < 4; i++) af[i]  = *(const bf16x8*)&As[(mrow + i * 16) * 32 + koct];
    #pragma unroll
    for (int j = 0; j < 4; j++) bfr[j] = *(const bf16x8*)&Bs[(nrow + j * 16) * 32 + koct];
    #pragma unroll
    for (int i = 0; i < 4; i++)
      #pragma unroll
      for (int j = 0; j < 4; j++)
        acc[i][j] = __builtin_amdgcn_mfma_f32_16x16x32_bf16(af[i], bfr[j], acc[i][j], 0, 0, 0);
    __syncthreads();
  }

  const int r0 = (lane >> 4) * 4;
  #pragma unroll
  for (int j = 0; j < 4; j++) {
    const int col = bn + wn + j * 16 + r16;
    const float bv = bias[col];
    #pragma unroll
    for (int i = 0; i < 4; i++) {
      const int rowb = bm + wm + i * 16 + r0;
      #pragma unroll
      for (int r = 0; r < 4; r++) {
        size_t ro = (size_t)(rowb + r) * N + col;
        float v = acc[i][j][r] + bv;
        if (RES) v += res[ro];
        st_out(out + ro, v);
      }
    }
  }
}

// ---------------- MFMA flash global attention ----------------
__global__ __launch_bounds__(256) void gattn_kernel(const bf16* __restrict__ q,
                                                    const bf16* __restrict__ kv,
                                                    bf16* __restrict__ out) {
  __shared__ __align__(16) bf16 Ks[256][40];
  __shared__ __align__(16) bf16 Vt[32][264];
  __shared__ __align__(16) bf16 Ps[4][32][40];
  const int tid = threadIdx.x;
  const int lane = tid & 63, w = tid >> 6;
  const int h = blockIdx.y, b = blockIdx.z;
  const int n0 = blockIdx.x * 128;
  const int r16 = lane & 15, oct = (lane >> 4) * 8;
  const bf16* kvb = kv + (size_t)b * TG_ * 256;

  {
    const int key = tid;
    const bf16* kp = kvb + (size_t)key * 256 + h * 32;
    *(uint4*)&Ks[key][0]  = *(const uint4*)(kp);
    *(uint4*)&Ks[key][8]  = *(const uint4*)(kp + 8);
    *(uint4*)&Ks[key][16] = *(const uint4*)(kp + 16);
    *(uint4*)&Ks[key][24] = *(const uint4*)(kp + 24);
    union { uint4 u[4]; bf16 e[32]; } vv;
    vv.u[0] = *(const uint4*)(kp + 128);
    vv.u[1] = *(const uint4*)(kp + 136);
    vv.u[2] = *(const uint4*)(kp + 144);
    vv.u[3] = *(const uint4*)(kp + 152);
    #pragma unroll
    for (int d = 0; d < 32; d++) Vt[d][key] = vv.e[d];
  }
  const size_t qbase0 = ((size_t)(b * Nn + n0 + w * 32 + r16)) * GD_ + h * 32 + oct;
  bf16x8 aq0 = *(const bf16x8*)(q + qbase0);
  bf16x8 aq1 = *(const bf16x8*)(q + qbase0 + (size_t)16 * GD_);
  __syncthreads();

  f32x4 rs0 = {0.f, 0.f, 0.f, 0.f}, rs1 = {0.f, 0.f, 0.f, 0.f};
  f32x4 ov[2][2];
  #pragma unroll
  for (int i = 0; i < 2; i++)
    #pragma unroll
    for (int dt = 0; dt < 2; dt++) ov[i][dt] = (f32x4){0.f, 0.f, 0.f, 0.f};

  for (int c0 = 0; c0 < 256; c0 += 32) {
    #pragma unroll
    for (int t = 0; t < 2; t++) {
      bf16x8 bk = *(const bf16x8*)&Ks[c0 + t * 16 + r16][oct];
      f32x4 s0 = __builtin_amdgcn_mfma_f32_16x16x32_bf16(aq0, bk, (f32x4){0.f,0.f,0.f,0.f}, 0, 0, 0);
      f32x4 s1 = __builtin_amdgcn_mfma_f32_16x16x32_bf16(aq1, bk, (f32x4){0.f,0.f,0.f,0.f}, 0, 0, 0);
      const int prow = (lane >> 4) * 4;
      const int pcol = t * 16 + r16;
      #pragma unroll
      for (int r = 0; r < 4; r++) {
        bf16 pb0 = __float2bfloat16(__expf(s0[r] * SCALE_));
        bf16 pb1 = __float2bfloat16(__expf(s1[r] * SCALE_));
        rs0[r] += toF(pb0);
        rs1[r] += toF(pb1);
        Ps[w][prow + r][pcol]      = pb0;
        Ps[w][16 + prow + r][pcol] = pb1;
      }
    }
    bf16x8 ap0 = *(const bf16x8*)&Ps[w][r16][oct];
    bf16x8 ap1 = *(const bf16x8*)&Ps[w][16 + r16][oct];
    #pragma unroll
    for (int dt = 0; dt < 2; dt++) {
      bf16x8 bv = *(const bf16x8*)&Vt[dt * 16 + r16][c0 + oct];
      ov[0][dt] = __builtin_amdgcn_mfma_f32_16x16x32_bf16(ap0, bv, ov[0][dt], 0, 0, 0);
      ov[1][dt] = __builtin_amdgcn_mfma_f32_16x16x32_bf16(ap1, bv, ov[1][dt], 0, 0, 0);
    }
  }
  #pragma unroll
  for (int off = 1; off < 16; off <<= 1) {
    #pragma unroll
    for (int r = 0; r < 4; r++) {
      rs0[r] += __shfl_xor(rs0[r], off);
      rs1[r] += __shfl_xor(rs1[r], off);
    }
  }
  const int orow0 = b * Nn + n0 + w * 32 + (lane >> 4) * 4;
  #pragma unroll
  for (int r = 0; r < 4; r++) {
    float inv0 = 1.0f / rs0[r];
    float inv1 = 1.0f / rs1[r];
    size_t ro0 = (size_t)(orow0 + r) * GD_ + h * 32;
    size_t ro1 = ro0 + (size_t)16 * GD_;
    #pragma unroll
    for (int dt = 0; dt < 2; dt++) {
      out[ro0 + dt * 16 + r16] = __float2bfloat16(ov[0][dt][r] * inv0);
      out[ro1 + dt * 16 + r16] = __float2bfloat16(ov[1][dt][r] * inv1);
    }
  }
}

// ---------------- local window attention: one wave per (b, window, head) ----------------
__global__ __launch_bounds__(64) void lattn_kernel(const bf16* __restrict__ ql,
                                                   const bf16* __restrict__ kvl,
                                                   bf16* __restrict__ out) {
  __shared__ float ks[T__ * 32];
  __shared__ float vs[T__ * 32];
  const int tid = threadIdx.x;
  const int h = blockIdx.x, g = blockIdx.y, b = blockIdx.z;
  const size_t base = (((size_t)b * TG_ + g) * T__) * 256;
  for (int idx = tid; idx < T__ * 32; idx += 64) {
    int m = idx >> 5, d = idx & 31;
    ks[idx] = toF(kvl[base + (size_t)m * 256 + h * 32 + d]);
    vs[idx] = toF(kvl[base + (size_t)m * 256 + 128 + h * 32 + d]);
  }
  __syncthreads();
  if (tid < T__) {
    const size_t qoff = (((size_t)b * TG_ + g) * T__ + tid) * LD_ + h * 32;
    float qv[32];
    #pragma unroll
    for (int d = 0; d < 32; d++) qv[d] = toF(ql[qoff + d]) * SCALE_;
    float l = 0.f;
    float acc[32] = {};
    for (int m = 0; m < T__; m++) {
      const float* kr = ks + m * 32;
      const float* vr = vs + m * 32;
      float s = 0.f;
      #pragma unroll
      for (int d = 0; d < 32; d++) s = fmaf(qv[d], kr[d], s);
      float p = __expf(fminf(s, 60.f));
      l += p;
      #pragma unroll
      for (int d = 0; d < 32; d++) acc[d] = fmaf(p, vr[d], acc[d]);
    }
    const float rl = 1.0f / l;
    #pragma unroll
    for (int d = 0; d < 32; d++) out[qoff + d] = __float2bfloat16(acc[d] * rl);
  }
}

// ---------------- combine + LN2 fused: wave per row, float4/lane ----------------
__global__ __launch_bounds__(256) void combine_ln_kernel(const float* __restrict__ x,
                                                         const bf16* __restrict__ gout,
                                                         const bf16* __restrict__ lo_w,
                                                         const float* __restrict__ g2,
                                                         const float* __restrict__ b2,
                                                         float* __restrict__ xres,
                                                         bf16* __restrict__ xn2) {
  const int tid = threadIdx.x;
  const int row = blockIdx.x * 4 + (tid >> 6);
  const int lane = tid & 63;
  const int c0 = lane * 4;
  int b = row / Nn, n = row - b * Nn;
  int y = n / Ww, xx = n - y * Ww;
  int gh = y / 7, i = y - gh * 7;
  int gw = xx / 7, j = xx - gw * 7;
  size_t wrow = ((size_t)b * TG_ + gh * 16 + gw) * T__ + i * 7 + j;
  union U4 { uint2 u; bf16 e[4]; } r4;
  if (lane < 32) r4.u = *(const uint2*)(gout + (size_t)row * GD_ + c0);
  else           r4.u = *(const uint2*)(lo_w + wrow * LD_ + (c0 - 128));
  float4 v = *(const float4*)(x + (size_t)row * Cc + c0);
  v.x += toF(r4.e[0]); v.y += toF(r4.e[1]); v.z += toF(r4.e[2]); v.w += toF(r4.e[3]);
  *(float4*)(xres + (size_t)row * Cc + c0) = v;
  float s  = v.x + v.y + v.z + v.w;
  float ss = v.x * v.x + v.y * v.y + v.z * v.z + v.w * v.w;
  #pragma unroll
  for (int off = 1; off < 64; off <<= 1) {
    s  += __shfl_xor(s, off);
    ss += __shfl_xor(ss, off);
  }
  float mean = s * (1.0f / Cc);
  float var  = ss * (1.0f / Cc) - mean * mean;
  float r = rsqrtf(var + 1e-5f);
  float4 gv = *(const float4*)(g2 + c0);
  float4 bv = *(const float4*)(b2 + c0);
  bf16 o[4];
  o[0] = __float2bfloat16((v.x - mean) * r * gv.x + bv.x);
  o[1] = __float2bfloat16((v.y - mean) * r * gv.y + bv.y);
  o[2] = __float2bfloat16((v.z - mean) * r * gv.z + bv.z);
  o[3] = __float2bfloat16((v.w - mean) * r * gv.w + bv.w);
  *(uint2*)(xn2 + (size_t)row * Cc + c0) = *(uint2*)o;
}

// ---------------- depthwise 3x3 conv + bias + exact GELU: sliding-window row walker ----------------
__global__ __launch_bounds__(256) void dwconv_gelu_kernel(const bf16* __restrict__ h1,
                                                          const float* __restrict__ w,
                                                          const float* __restrict__ bias,
                                                          bf16* __restrict__ h2) {
  const int tid = threadIdx.x;
  const int c0 = tid * 4;
  const int img = blockIdx.z, y = blockIdx.y;
  const int xt = blockIdx.x * 28;
  const size_t ibase = (size_t)img * Nn * HID_;

  float wreg[9][4], breg[4];
  #pragma unroll
  for (int u = 0; u < 4; u++) {
    breg[u] = bias[c0 + u];
    #pragma unroll
    for (int t = 0; t < 9; t++) wreg[t][u] = w[(c0 + u) * 9 + t];
  }

  const bf16* rowp[3];
  bool rok[3];
  #pragma unroll
  for (int r = 0; r < 3; r++) {
    int yy = y - 1 + r;
    rok[r] = (yy >= 0 && yy < Hh);
    rowp[r] = h1 + ibase + (size_t)(rok[r] ? yy : 0) * Ww * HID_ + c0;
  }

  float wa[3][4], wb[3][4], wc[3][4];
  union U4 { ushort2 u2[2]; bf16 e[4]; };
  auto loadcol = [&](int xcol, float v[3][4]) {
    if (xcol < 0 || xcol >= Ww) {
      #pragma unroll
      for (int r = 0; r < 3; r++)
        #pragma unroll
        for (int u = 0; u < 4; u++) v[r][u] = 0.f;
      return;
    }
    #pragma unroll
    for (int r = 0; r < 3; r++) {
      if (rok[r]) {
        U4 raw;
        *(uint2*)&raw = *(const uint2*)(rowp[r] + (size_t)xcol * HID_);
        #pragma unroll
        for (int u = 0; u < 4; u++) v[r][u] = toF(raw.e[u]);
      } else {
        #pragma unroll
        for (int u = 0; u < 4; u++) v[r][u] = 0.f;
      }
    }
  };
  loadcol(xt - 1, wa);
  loadcol(xt, wb);

  for (int xx = 0; xx < 28; xx++) {
    const int x = xt + xx;
    loadcol(x + 1, wc);
    bf16 res[4];
    #pragma unroll
    for (int u = 0; u < 4; u++) {
      float a = breg[u];
      a = fmaf(wa[0][u], wreg[0][u], a);
      a = fmaf(wb[0][u], wreg[1][u], a);
      a = fmaf(wc[0][u], wreg[2][u], a);
      a = fmaf(wa[1][u], wreg[3][u], a);
      a = fmaf(wb[1][u], wreg[4][u], a);
      a = fmaf(wc[1][u], wreg[5][u], a);
      a = fmaf(wa[2][u], wreg[6][u], a);
      a = fmaf(wb[2][u], wreg[7][u], a);
      a = fmaf(wc[2][u], wreg[8][u], a);
      float gl = 0.5f * a * (1.0f + erff(a * 0.7071067811865475f));
      res[u] = __float2bfloat16(gl);
    }
    *(uint2*)(h2 + ibase + (size_t)(y * Ww + x) * HID_ + c0) = *(uint2*)res;
    #pragma unroll
    for (int r = 0; r < 3; r++)
      #pragma unroll
      for (int u = 0; u < 4; u++) { wa[r][u] = wb[r][u]; wb[r][u] = wc[r][u]; }
  }
}

extern "C" void kernel_launch(void* const* d_in, const int* in_sizes, int n_in,
                              void* d_out, int out_size, void* d_ws, size_t ws_size,
                              hipStream_t stream) {
  const float* x     = (const float*)d_in[0];
  const float* xrev  = (const float*)d_in[1];
  const float* g1    = (const float*)d_in[2];
  const float* b1    = (const float*)d_in[3];
  const float* g2    = (const float*)d_in[4];
  const float* b2    = (const float*)d_in[5];
  const float* Gq_w  = (const float*)d_in[6];
  const float* Gq_b  = (const float*)d_in[7];
  const float* Gkv_w = (const float*)d_in[8];
  const float* Gkv_b = (const float*)d_in[9];
  const float* Gp_w  = (const float*)d_in[10];
  const float* Gp_b  = (const float*)d_in[11];
  const float* Lq_w  = (const float*)d_in[12];
  const float* Lq_b  = (const float*)d_in[13];
  const float* Lkv_w = (const float*)d_in[14];
  const float* Lkv_b = (const float*)d_in[15];
  const float* Lp_w  = (const float*)d_in[16];
  const float* Lp_b  = (const float*)d_in[17];
  const float* fc1_w = (const float*)d_in[18];
  const float* fc1_b = (const float*)d_in[19];
  const float* dw_w  = (const float*)d_in[20];
  const float* dw_b  = (const float*)d_in[21];
  const float* fc2_w = (const float*)d_in[22];
  const float* fc2_b = (const float*)d_in[23];

  // ---- transposed bf16 weight arena ----
  const size_t E_GQ = 256 * 128, E_GKV = 256 * 256, E_GP = 128 * 128;
  const size_t E_LQ = 256 * 128, E_LKV = 256 * 256, E_LP = 128 * 128;
  const size_t E_F1 = 256 * 1024, E_F2 = 1024 * 256;
  char* ws = (char*)d_ws;
  bf16* Gq_t  = (bf16*)ws;
  bf16* Gkv_t = Gq_t  + E_GQ;
  bf16* Gp_t  = Gkv_t + E_GKV;
  bf16* Lq_t  = Gp_t  + E_GP;
  bf16* Lkv_t = Lq_t  + E_LQ;
  bf16* Lp_t  = Lkv_t + E_LKV;
  bf16* f1_t  = Lp_t  + E_LP;
  bf16* f2_t  = f1_t  + E_F1;
  const size_t WT_ELEMS = E_GQ + E_GKV + E_GP + E_LQ + E_LKV + E_LP + E_F1 + E_F2;
  const size_t WT_BYTES = WT_ELEMS * 2;

  // ---- activation arena ----
  const size_t SZ_ROW2 = (size_t)M_ * Cc * 2;
  const size_t SZ_HALF = (size_t)M_ * 128 * 2;
  const size_t SZ_POOL = (size_t)B_ * TG_ * Cc * 2;
  const size_t SZ_KVG  = (size_t)B_ * TG_ * 256 * 2;
  const size_t SZ_H    = (size_t)(2 * Nn) * HID_ * 2;
  char* arena = ws + WT_BYTES;
  bf16* S1 = (bf16*)(arena);
  bf16* S2 = (bf16*)(arena + SZ_ROW2);
  bf16* S3 = (bf16*)(arena + 2 * SZ_ROW2);
  bf16* S4 = (bf16*)(arena + 2 * SZ_ROW2 + SZ_HALF);
  bf16* S5 = (bf16*)(arena + 2 * SZ_ROW2 + 2 * SZ_HALF);
  bf16* poolb = (bf16*)(arena + 2 * SZ_ROW2 + 3 * SZ_HALF);
  bf16* kvG   = (bf16*)(arena + 2 * SZ_ROW2 + 3 * SZ_HALF + SZ_POOL);
  const size_t ARENA_A = 2 * SZ_ROW2 + 3 * SZ_HALF + SZ_POOL + SZ_KVG;
  bf16* xn2 = S1;
  bf16* h1  = (bf16*)(arena + SZ_ROW2);
  bf16* h2  = (bf16*)(arena + SZ_ROW2 + SZ_H);
  const size_t ARENA_B = SZ_ROW2 + 2 * SZ_H;

  float* out  = (float*)d_out;
  float* xres = (float*)d_out;
  const size_t NEED = WT_BYTES + (ARENA_A > ARENA_B ? ARENA_A : ARENA_B);
  if (ws_size < NEED) {
    guard_fill_kernel<<<16, 256, 0, stream>>>(out);
    return;
  }

  bf16* xn = S1;  bf16* xrn = S2;  bf16* qbuf = S3;  bf16* gattn = S4;  bf16* gout = S5;
  bf16* kvl = S1; bf16* lo_w = S2; bf16* qlb  = S3;  bf16* lattn = S4;

  // 0) all weights -> bf16 transposed, one kernel
  convert_all_kernel<<<2944, 256, 0, stream>>>(Gq_w, Gkv_w, Gp_w, Lq_w, Lkv_w, Lp_w,
                                               fc1_w, fc2_w, (bf16*)ws);
  // 1) LayerNorm both streams, one launch (wave-per-row)
  ln_dual_kernel<<<dim3(M_ / 4, 2), 256, 0, stream>>>(x, xrev, g1, b1, xn, xrn);
  // 2) 7x7 pool of xrn
  pool_kernel<<<dim3(TG_, B_), 64, 0, stream>>>(xrn, poolb);
  // 3) q = xn @ Gq_w + b
  mfma_gemm_kernel<bf16, false, false><<<dim3(1, M_ / 128), 256, 0, stream>>>(
      xn, Gq_t, Gq_b, nullptr, qbuf, M_, 128, 256);
  // 4) kv = pooled @ Gkv_w + b
  mfma_gemm_kernel<bf16, false, false><<<dim3(2, 8), 256, 0, stream>>>(
      poolb, Gkv_t, Gkv_b, nullptr, kvG, 1024, 256, 256);
  // 5) global attention (MFMA flash)
  gattn_kernel<<<dim3(Nn / 128, GH_, B_), 256, 0, stream>>>(qbuf, kvG, gattn);
  // 6) gout = gattn @ Gp_w + b
  mfma_gemm_kernel<bf16, false, false><<<dim3(1, M_ / 128), 256, 0, stream>>>(
      gattn, Gp_t, Gp_b, nullptr, gout, M_, 128, 128);
  // 7) ql = windows(xn) @ Lq_w + b
  mfma_gemm_kernel<bf16, true, false><<<dim3(1, M_ / 128), 256, 0, stream>>>(
      xn, Lq_t, Lq_b, nullptr, qlb, M_, 128, 256);
  // 8) kvl = windows(xrn) @ Lkv_w + b
  mfma_gemm_kernel<bf16, true, false><<<dim3(2, M_ / 128), 256, 0, stream>>>(
      xrn, Lkv_t, Lkv_b, nullptr, kvl, M_, 256, 256);
  // 9) local attention
  lattn_kernel<<<dim3(4, TG_, B_), 64, 0, stream>>>(qlb, kvl, lattn);
  // 10) lo = lattn @ Lp_w + b
  mfma_gemm_kernel<bf16, false, false><<<dim3(1, M_ / 128), 256, 0, stream>>>(
      lattn, Lp_t, Lp_b, nullptr, lo_w, M_, 128, 128);
  // 11) xres(=d_out) = x + concat(gout, unwin(lo)); xn2 = LN2(xres)  [fused, wave-per-row]
  combine_ln_kernel<<<M_ / 4, 256, 0, stream>>>(x, gout, lo_w, g2, b2, xres, xn2);
  // 12-14) MLP in two halves (2 images each)
  for (int half = 0; half < 2; half++) {
    const size_t r0 = (size_t)half * 2 * Nn;
    mfma_gemm_kernel<bf16, false, false><<<dim3(8, (2 * Nn) / 128), 256, 0, stream>>>(
        xn2 + r0 * Cc, f1_t, fc1_b, nullptr, h1, 2 * Nn, 1024, 256);
    dwconv_gelu_kernel<<<dim3(4, Hh, 2), 256, 0, stream>>>(h1, dw_w, dw_b, h2);
    mfma_gemm_kernel<float, false, true><<<dim3(2, (2 * Nn) / 128), 256, 0, stream>>>(
        h2, f2_t, fc2_b, xres + r0 * Cc, out + r0 * Cc, 2 * Nn, 256, 1024);
  }
}